// Round 13
// baseline (156.115 us; speedup 1.0000x reference)
//
#include <hip/hip_runtime.h>
#include <math.h>

constexpr int NB = 2;           // batch
constexpr int IMG = 64;         // H == W
constexpr int CH = 128;         // channels
constexpr int NT = IMG * IMG;   // 4096 tokens per batch
constexpr int ATT_KSPLIT = 8;
constexpr int KPS = NT / ATT_KSPLIT;  // 512 keys per split

typedef __bf16 bf16x8 __attribute__((ext_vector_type(8)));
typedef float f32x4 __attribute__((ext_vector_type(4)));

__device__ __forceinline__ unsigned f2bf(float x) {  // RNE float->bf16 bits
  unsigned u = __float_as_uint(x);
  return (u + 0x7fffu + ((u >> 16) & 1u)) >> 16;
}
__device__ __forceinline__ float bf2f(unsigned h) {
  return __uint_as_float(h << 16);
}
__device__ __forceinline__ float maskval(float mk) {
  float mm = mk > 0.f ? 0.f : mk;
  return (1.f - mm) * (1.f - mk);
}

// ---------------------------------------------------------------- weight prep (sliced, 232 blocks)
__global__ __launch_bounds__(256) void k_prepw(
    const float* __restrict__ rw1, const float* __restrict__ rw2,
    const float* __restrict__ wt_, const float* __restrict__ wp_,
    const float* __restrict__ wg_, const float* __restrict__ ww_,
    unsigned short* __restrict__ wfrag) {
  __shared__ float Ws[32][132];
  const int t = threadIdx.x;
  const int tile = blockIdx.x >> 2, slice = blockIdx.x & 3;
  const float* src;
  if (tile < 54) {
    int i2 = tile / 9, tap = tile - i2 * 9;
    int blk = i2 >> 1;
    src = ((i2 & 1) ? rw2 : rw1) + ((size_t)blk * 9 + tap) * 16384;
  } else {
    src = tile == 54 ? wt_ : tile == 55 ? wp_ : tile == 56 ? wg_ : ww_;
  }
#pragma unroll
  for (int k = 0; k < 4; ++k) {
    int i4 = t + 256 * k;
    int row = i4 >> 5, c4 = (i4 & 31) << 2;
    *(float4*)&Ws[row][c4] =
        *(const float4*)(src + (size_t)(slice * 32 + row) * 128 + c4);
  }
  __syncthreads();
  unsigned short* dst = wfrag + (size_t)tile * 16384;
#pragma unroll
  for (int i = 0; i < 2; ++i) {
    int it = t + 256 * i;  // 0..511: cotile*64 + lane
    int cotile = it >> 6, lane = it & 63;
    int lg = lane >> 4, lc = lane & 15;
    int co = cotile * 16 + lc, r0 = lg * 8;  // local ci row
    unsigned u0 = f2bf(Ws[r0 + 0][co]) | (f2bf(Ws[r0 + 1][co]) << 16);
    unsigned u1 = f2bf(Ws[r0 + 2][co]) | (f2bf(Ws[r0 + 3][co]) << 16);
    unsigned u2 = f2bf(Ws[r0 + 4][co]) | (f2bf(Ws[r0 + 5][co]) << 16);
    unsigned u3 = f2bf(Ws[r0 + 6][co]) | (f2bf(Ws[r0 + 7][co]) << 16);
    int idx = cotile * 256 + slice * 64 + lane;
    *(uint4*)(dst + (size_t)idx * 8) = make_uint4(u0, u1, u2, u3);
  }
}

// ---------------------------------------------------------------- fused projections (round-5 form)
__global__ __launch_bounds__(256) void k_proj3(
    const float* __restrict__ x, const float* __restrict__ mask,
    const unsigned short* __restrict__ wf, const float* __restrict__ bt_,
    const float* __restrict__ bp_, const float* __restrict__ bg_,
    unsigned short* __restrict__ thb, unsigned short* __restrict__ phb,
    unsigned short* __restrict__ vtb) {
  __shared__ __align__(16) unsigned short Al[64 * 136];
  __shared__ __align__(16) unsigned short Tl[64 * 136];
  const int t = threadIdx.x, r0 = blockIdx.x * 64, b = r0 >> 12;

#pragma unroll
  for (int k = 0; k < 4; ++k) {
    int it = t + 256 * k;
    int row = it >> 4, g = it & 15;
    const float* s = x + (size_t)(r0 + row) * 128 + g * 8;
    float4 v0 = *(const float4*)s, v1 = *(const float4*)(s + 4);
    uint4 pk;
    pk.x = f2bf(v0.x) | (f2bf(v0.y) << 16);
    pk.y = f2bf(v0.z) | (f2bf(v0.w) << 16);
    pk.z = f2bf(v1.x) | (f2bf(v1.y) << 16);
    pk.w = f2bf(v1.z) | (f2bf(v1.w) << 16);
    *(uint4*)&Al[row * 136 + g * 8] = pk;
  }
  __syncthreads();

  const int w = t >> 6, lane = t & 63, lg = lane >> 4, lc = lane & 15;
  const int mw = w & 1, nw = w >> 1;
#pragma unroll
  for (int mat = 0; mat < 3; ++mat) {
    f32x4 acc[2][4];
#pragma unroll
    for (int m = 0; m < 2; ++m)
#pragma unroll
      for (int n = 0; n < 4; ++n)
#pragma unroll
        for (int r = 0; r < 4; ++r) acc[m][n][r] = 0.f;
    const unsigned short* wb =
        wf + (size_t)(54 + mat) * 16384 + (size_t)(nw * 4) * 2048 + lane * 8;
#pragma unroll
    for (int k = 0; k < 4; ++k) {
      bf16x8 a0 = *(const bf16x8*)&Al[(mw * 32 + lc) * 136 + k * 32 + lg * 8];
      bf16x8 a1 = *(const bf16x8*)&Al[(mw * 32 + 16 + lc) * 136 + k * 32 + lg * 8];
#pragma unroll
      for (int n = 0; n < 4; ++n) {
        bf16x8 bfr = *(const bf16x8*)(wb + n * 2048 + k * 512);
        acc[0][n] = __builtin_amdgcn_mfma_f32_16x16x32_bf16(a0, bfr, acc[0][n], 0, 0, 0);
        acc[1][n] = __builtin_amdgcn_mfma_f32_16x16x32_bf16(a1, bfr, acc[1][n], 0, 0, 0);
      }
    }
    const float* bs = mat == 0 ? bt_ : mat == 1 ? bp_ : bg_;
    float bbv[4];
#pragma unroll
    for (int n = 0; n < 4; ++n) bbv[n] = bs[nw * 64 + n * 16 + lc];

    if (mat < 2) {
      unsigned short* ob = mat == 0 ? thb : phb;
#pragma unroll
      for (int n = 0; n < 4; ++n) {
        int col = nw * 64 + n * 16 + lc;
#pragma unroll
        for (int m = 0; m < 2; ++m)
#pragma unroll
          for (int r = 0; r < 4; ++r) {
            int row = r0 + mw * 32 + m * 16 + lg * 4 + r;
            ob[(size_t)row * 128 + col] = (unsigned short)f2bf(acc[m][n][r] + bbv[n]);
          }
      }
    } else {
#pragma unroll
      for (int m = 0; m < 2; ++m)
#pragma unroll
        for (int r = 0; r < 4; ++r) {
          int rl = mw * 32 + m * 16 + lg * 4 + r;
          float mvv = maskval(mask[r0 + rl]);
#pragma unroll
          for (int n = 0; n < 4; ++n) {
            int col = nw * 64 + n * 16 + lc;
            Tl[rl * 136 + col] = (unsigned short)f2bf((acc[m][n][r] + bbv[n]) * mvv);
          }
        }
      __syncthreads();
      const int c = t >> 1, h = t & 1;
      unsigned buf[16];
#pragma unroll
      for (int j = 0; j < 16; ++j)
        buf[j] = (unsigned)Tl[(h * 32 + 2 * j) * 136 + c] |
                 ((unsigned)Tl[(h * 32 + 2 * j + 1) * 136 + c] << 16);
      const int key0 = r0 & (NT - 1);
      unsigned short* dst = vtb + ((size_t)b * CH + c) * NT + key0 + h * 32;
      uint4* d4 = (uint4*)dst;
#pragma unroll
      for (int q = 0; q < 4; ++q)
        d4[q] = make_uint4(buf[4 * q], buf[4 * q + 1], buf[4 * q + 2], buf[4 * q + 3]);
    }
  }
}

// ---------------------------------------------------------------- flash attention (round-12 exact)
__global__ __launch_bounds__(256, 2) void k_attn(
    const unsigned short* __restrict__ theta, const unsigned short* __restrict__ phi,
    const unsigned short* __restrict__ vt, unsigned short* __restrict__ partO,
    float* __restrict__ partL) {
  __shared__ __align__(16) unsigned short Klds[64][136];
  __shared__ __align__(16) unsigned short Vtlds[128][72];
  __shared__ __align__(16) unsigned short Plds[4][32][72];

  const int t = threadIdx.x;
  const int bx = blockIdx.x;
  const int qt = bx & 31;
  const int ks = (bx >> 5) & 7;
  const int b = bx >> 8;
  const int w = t >> 6;
  const int lane = t & 63;
  const int lg = lane >> 4;
  const int lc = lane & 15;
  const int q0 = qt * 128 + w * 32;

  const unsigned short* thB = theta + (size_t)b * NT * CH;
  const unsigned short* phB = phi + (size_t)b * NT * CH;
  const unsigned short* vtB = vt + (size_t)b * CH * NT;

  bf16x8 qf[2][4];
#pragma unroll
  for (int q2 = 0; q2 < 2; ++q2)
#pragma unroll
    for (int k = 0; k < 4; ++k)
      qf[q2][k] = *(const bf16x8*)(thB + (size_t)(q0 + q2 * 16 + lc) * CH + k * 32 + lg * 8);

  f32x4 oacc[2][8];
#pragma unroll
  for (int q2 = 0; q2 < 2; ++q2)
#pragma unroll
    for (int c = 0; c < 8; ++c)
#pragma unroll
      for (int r = 0; r < 4; ++r) oacc[q2][c][r] = 0.f;
  float lsum[2][4] = {{0.f, 0.f, 0.f, 0.f}, {0.f, 0.f, 0.f, 0.f}};

  for (int kt = 0; kt < KPS; kt += 64) {
    const int key0 = ks * KPS + kt;
    __syncthreads();
#pragma unroll
    for (int i = 0; i < 4; ++i) {
      int idx = t + 256 * i;
      int row = idx >> 4, c8 = (idx & 15) * 8;
      *(uint4*)&Klds[row][c8] = *(const uint4*)(phB + (size_t)(key0 + row) * CH + c8);
      int rowv = idx >> 3, k8 = (idx & 7) * 8;
      *(uint4*)&Vtlds[rowv][k8] = *(const uint4*)(vtB + (size_t)rowv * NT + key0 + k8);
    }
    __syncthreads();

#pragma unroll
    for (int col = 0; col < 4; ++col) {
      bf16x8 kf[4];
#pragma unroll
      for (int k = 0; k < 4; ++k)
        kf[k] = *(const bf16x8*)&Klds[col * 16 + lc][k * 32 + lg * 8];
      f32x4 s0, s1;
#pragma unroll
      for (int r = 0; r < 4; ++r) { s0[r] = 0.f; s1[r] = 0.f; }
#pragma unroll
      for (int k = 0; k < 4; ++k) {
        s0 = __builtin_amdgcn_mfma_f32_16x16x32_bf16(qf[0][k], kf[k], s0, 0, 0, 0);
        s1 = __builtin_amdgcn_mfma_f32_16x16x32_bf16(qf[1][k], kf[k], s1, 0, 0, 0);
      }
#pragma unroll
      for (int r = 0; r < 4; ++r) {
        float p0 = __expf(s0[r]);
        lsum[0][r] += p0;
        Plds[w][lg * 4 + r][col * 16 + lc] = (unsigned short)f2bf(p0);
        float p1 = __expf(s1[r]);
        lsum[1][r] += p1;
        Plds[w][16 + lg * 4 + r][col * 16 + lc] = (unsigned short)f2bf(p1);
      }
    }

#pragma unroll
    for (int kp = 0; kp < 2; ++kp) {
      bf16x8 pa0 = *(const bf16x8*)&Plds[w][lc][kp * 32 + lg * 8];
      bf16x8 pa1 = *(const bf16x8*)&Plds[w][16 + lc][kp * 32 + lg * 8];
#pragma unroll
      for (int col = 0; col < 8; ++col) {
        bf16x8 vf = *(const bf16x8*)&Vtlds[col * 16 + lc][kp * 32 + lg * 8];
        oacc[0][col] = __builtin_amdgcn_mfma_f32_16x16x32_bf16(pa0, vf, oacc[0][col], 0, 0, 0);
        oacc[1][col] = __builtin_amdgcn_mfma_f32_16x16x32_bf16(pa1, vf, oacc[1][col], 0, 0, 0);
      }
    }
  }

#pragma unroll
  for (int off = 1; off < 16; off <<= 1)
#pragma unroll
    for (int q2 = 0; q2 < 2; ++q2)
#pragma unroll
      for (int r = 0; r < 4; ++r) lsum[q2][r] += __shfl_xor(lsum[q2][r], off);

  const size_t obase = ((size_t)ks * NB + b) * NT;
#pragma unroll
  for (int q2 = 0; q2 < 2; ++q2) {
#pragma unroll
    for (int col = 0; col < 8; ++col)
#pragma unroll
      for (int r = 0; r < 4; ++r) {
        int row = q0 + q2 * 16 + lg * 4 + r;
        partO[(obase + row) * CH + col * 16 + lc] = (unsigned short)f2bf(oacc[q2][col][r]);
      }
    if (lc == 0) {
#pragma unroll
      for (int r = 0; r < 4; ++r)
        partL[obase + q0 + q2 * 16 + lg * 4 + r] = lsum[q2][r];
    }
  }
}

// ---------------------------------------------------------------- W gemm + combine (round-5 form)
__global__ __launch_bounds__(256) void k_gemmW(
    const unsigned short* __restrict__ partO, const float* __restrict__ partL,
    const unsigned short* __restrict__ wf, const float* __restrict__ bias,
    float* __restrict__ wy, unsigned short* __restrict__ wyb) {
  __shared__ __align__(16) unsigned short Al[64 * 136];
  __shared__ float linv[64];
  const int t = threadIdx.x, r0 = blockIdx.x * 64;

  if (t < 64) {
    float l = 0.f;
#pragma unroll
    for (int ks = 0; ks < ATT_KSPLIT; ++ks) l += partL[(size_t)ks * 8192 + r0 + t];
    linv[t] = 1.f / l;
  }
  __syncthreads();

#pragma unroll
  for (int i = 0; i < 4; ++i) {
    int it = t + 256 * i;
    int row = it >> 4, g = it & 15;
    float a[8] = {0.f, 0.f, 0.f, 0.f, 0.f, 0.f, 0.f, 0.f};
#pragma unroll
    for (int ks = 0; ks < ATT_KSPLIT; ++ks) {
      uint4 u = *(const uint4*)(partO + ((size_t)ks * 8192 + r0 + row) * 128 + g * 8);
      const unsigned* uw = (const unsigned*)&u;
#pragma unroll
      for (int q = 0; q < 4; ++q) {
        a[2 * q] += bf2f(uw[q] & 0xffffu);
        a[2 * q + 1] += bf2f(uw[q] >> 16);
      }
    }
    float s = linv[row];
    uint4 pk;
    pk.x = f2bf(a[0] * s) | (f2bf(a[1] * s) << 16);
    pk.y = f2bf(a[2] * s) | (f2bf(a[3] * s) << 16);
    pk.z = f2bf(a[4] * s) | (f2bf(a[5] * s) << 16);
    pk.w = f2bf(a[6] * s) | (f2bf(a[7] * s) << 16);
    *(uint4*)&Al[row * 136 + g * 8] = pk;
  }
  __syncthreads();

  const int w = t >> 6, lane = t & 63, lg = lane >> 4, lc = lane & 15;
  const int mw = w & 1, nw = w >> 1;
  f32x4 acc[2][4];
#pragma unroll
  for (int m = 0; m < 2; ++m)
#pragma unroll
    for (int n = 0; n < 4; ++n)
#pragma unroll
      for (int r = 0; r < 4; ++r) acc[m][n][r] = 0.f;
  const unsigned short* wb =
      wf + (size_t)57 * 16384 + (size_t)(nw * 4) * 2048 + lane * 8;
#pragma unroll
  for (int k = 0; k < 4; ++k) {
    bf16x8 a0 = *(const bf16x8*)&Al[(mw * 32 + lc) * 136 + k * 32 + lg * 8];
    bf16x8 a1 = *(const bf16x8*)&Al[(mw * 32 + 16 + lc) * 136 + k * 32 + lg * 8];
#pragma unroll
    for (int n = 0; n < 4; ++n) {
      bf16x8 bfr = *(const bf16x8*)(wb + n * 2048 + k * 512);
      acc[0][n] = __builtin_amdgcn_mfma_f32_16x16x32_bf16(a0, bfr, acc[0][n], 0, 0, 0);
      acc[1][n] = __builtin_amdgcn_mfma_f32_16x16x32_bf16(a1, bfr, acc[1][n], 0, 0, 0);
    }
  }
#pragma unroll
  for (int n = 0; n < 4; ++n) {
    int col = nw * 64 + n * 16 + lc;
    float bb = bias[col];
#pragma unroll
    for (int m = 0; m < 2; ++m)
#pragma unroll
      for (int r = 0; r < 4; ++r) {
        int row = r0 + mw * 32 + m * 16 + lg * 4 + r;
        float v = acc[m][n][r] + bb;
        wy[(size_t)row * 128 + col] = v;
        wyb[(size_t)row * 128 + col] = (unsigned short)f2bf(v);
      }
  }
}

// ---------------------------------------------------------------- 3x3 reflect conv (bf16 MFMA)
// Block = one image row (64 px) x 64 co, 256 threads / 4 waves; wave = 64 px x 16 co.
// Halves per-block weight fragment traffic (144 KB vs 288 KB) vs 32-px blocks.
// MODE 0: plain bf16 input. MODE 1: relu(IN(input)). MODE 2: wy_in + IN(c2) fused residual.
template <int MODE>
__global__ __launch_bounds__(256, 2) void k_conv(
    const unsigned short* __restrict__ act, const unsigned short* __restrict__ wf,
    const float* __restrict__ bias, const float* __restrict__ part_in,
    const float* __restrict__ gamma, const float* __restrict__ beta,
    unsigned short* __restrict__ outc, float* __restrict__ part_out,
    const float* __restrict__ wy_in, float* __restrict__ wy_out) {
  __shared__ unsigned short Alds[3][66 * 136];
  __shared__ float red[256];
  __shared__ float Aff[2][128];

  const int t = threadIdx.x, bx = blockIdx.x;
  const int coh = bx & 1, y = (bx >> 1) & 63, b = bx >> 7;
  const int w = t >> 6, lane = t & 63, lg = lane >> 4, lc = lane & 15;
  const int coT = coh * 4 + w;  // global 16-co tile 0..7

  if constexpr (MODE >= 1) {
    const float4* p = (const float4*)(part_in + ((size_t)b * 256 + t) * 64);
    float s0 = 0.f, s1 = 0.f, s2 = 0.f, s3 = 0.f;
#pragma unroll 8
    for (int k = 0; k < 16; ++k) {
      float4 v = p[k];
      s0 += v.x; s1 += v.y; s2 += v.z; s3 += v.w;
    }
    red[t] = (s0 + s1) + (s2 + s3);
    __syncthreads();
    if (t < 128) {
      float mean = red[2 * t] * (1.f / 4096.f);
      float var = red[2 * t + 1] * (1.f / 4096.f) - mean * mean;
      float a = gamma[t] * rsqrtf(var + 1e-3f);
      Aff[0][t] = a;
      Aff[1][t] = beta[t] - mean * a;
    }
    __syncthreads();
  }

  // stage 3 reflect rows x 66 px x 128 ch
  const unsigned short* actB = act + (size_t)b * NT * CH;
#pragma unroll
  for (int i = 0; i < 13; ++i) {
    int it = t + 256 * i;
    if (it < 3168) {
      int r = it / 1056, rem = it - r * 1056;
      int px = rem >> 4, g = rem & 15;
      int sy = y - 1 + r;
      sy = sy < 0 ? 1 : (sy > 63 ? 62 : sy);
      int sx = px - 1;
      sx = sx < 0 ? 1 : (sx > 63 ? 62 : sx);
      const int lpix = sy * 64 + sx;
      uint4 v = *(const uint4*)(actB + (size_t)lpix * CH + g * 8);
      if constexpr (MODE == 1) {
        int c0 = g * 8;
        unsigned* vw = (unsigned*)&v;
#pragma unroll
        for (int q = 0; q < 4; ++q) {
          float v0 = bf2f(vw[q] & 0xffffu), v1 = bf2f(vw[q] >> 16);
          v0 = fmaxf(0.f, fmaf(Aff[0][c0 + 2 * q], v0, Aff[1][c0 + 2 * q]));
          v1 = fmaxf(0.f, fmaf(Aff[0][c0 + 2 * q + 1], v1, Aff[1][c0 + 2 * q + 1]));
          vw[q] = f2bf(v0) | (f2bf(v1) << 16);
        }
      } else if constexpr (MODE == 2) {
        int c0 = g * 8;
        const size_t gpix = (size_t)b * NT + lpix;
        const float* wpin = wy_in + gpix * CH + c0;
        float4 w0 = *(const float4*)wpin, w1 = *(const float4*)(wpin + 4);
        float wv[8] = {w0.x, w0.y, w0.z, w0.w, w1.x, w1.y, w1.z, w1.w};
        const unsigned* vw = (const unsigned*)&v;
        float o[8];
#pragma unroll
        for (int q = 0; q < 8; ++q) {
          float cv = bf2f((q & 1) ? (vw[q >> 1] >> 16) : (vw[q >> 1] & 0xffffu));
          o[q] = wv[q] + fmaf(Aff[0][c0 + q], cv, Aff[1][c0 + q]);
        }
        // own row, interior px, own channel half: write residual f32 exactly once
        if (r == 1 && px >= 1 && px < 65 && (g >> 3) == coh) {
          float* wpo = wy_out + gpix * CH + c0;
          *(float4*)wpo = make_float4(o[0], o[1], o[2], o[3]);
          *(float4*)(wpo + 4) = make_float4(o[4], o[5], o[6], o[7]);
        }
        uint4 pk;
        pk.x = f2bf(o[0]) | (f2bf(o[1]) << 16);
        pk.y = f2bf(o[2]) | (f2bf(o[3]) << 16);
        pk.z = f2bf(o[4]) | (f2bf(o[5]) << 16);
        pk.w = f2bf(o[6]) | (f2bf(o[7]) << 16);
        v = pk;
      }
      *(uint4*)&Alds[r][px * 136 + g * 8] = v;
    }
  }
  __syncthreads();

  f32x4 acc[4];
#pragma unroll
  for (int m = 0; m < 4; ++m)
#pragma unroll
    for (int r = 0; r < 4; ++r) acc[m][r] = 0.f;

  const unsigned short* wbase = wf + (size_t)coT * 2048 + lane * 8;
  bf16x8 wc[4], wn[4];
#pragma unroll
  for (int k = 0; k < 4; ++k) wc[k] = *(const bf16x8*)(wbase + k * 512);
#pragma unroll
  for (int tap = 0; tap < 9; ++tap) {
    const int dy = tap / 3, dx = tap - dy * 3;
    if (tap < 8) {
#pragma unroll
      for (int k = 0; k < 4; ++k)
        wn[k] = *(const bf16x8*)(wbase + (size_t)(tap + 1) * 16384 + k * 512);
    }
#pragma unroll
    for (int k = 0; k < 4; ++k) {
#pragma unroll
      for (int m = 0; m < 4; ++m) {
        bf16x8 a = *(const bf16x8*)&Alds[dy][(dx + m * 16 + lc) * 136 + k * 32 + lg * 8];
        acc[m] = __builtin_amdgcn_mfma_f32_16x16x32_bf16(a, wc[k], acc[m], 0, 0, 0);
      }
    }
#pragma unroll
    for (int k = 0; k < 4; ++k) wc[k] = wn[k];
  }

  const int col = coT * 16 + lc;
  const float bs = bias[col];
  float sum = 0.f, sq = 0.f;
  unsigned short* outB = outc + (size_t)(b * NT + y * 64) * CH;
#pragma unroll
  for (int m = 0; m < 4; ++m)
#pragma unroll
    for (int r = 0; r < 4; ++r) {
      float v = acc[m][r] + bs;
      int px = m * 16 + lg * 4 + r;
      outB[(size_t)px * CH + col] = (unsigned short)f2bf(v);
      sum += v;
      sq = fmaf(v, v, sq);
    }
  sum += __shfl_xor(sum, 16);
  sum += __shfl_xor(sum, 32);
  sq += __shfl_xor(sq, 16);
  sq += __shfl_xor(sq, 32);
  if (lg == 0) {
    part_out[((size_t)(b * 128 + col) * 2 + 0) * 64 + y] = sum;
    part_out[((size_t)(b * 128 + col) * 2 + 1) * 64 + y] = sq;
  }
}

// ---------------------------------------------------------------- final residual (+stats reduce, +blend)
__global__ __launch_bounds__(256) void k_residual_final(
    const unsigned short* __restrict__ c2v, const float* __restrict__ part_in,
    const float* __restrict__ gamma, const float* __restrict__ beta,
    const float* __restrict__ wy, const float* __restrict__ x,
    const float* __restrict__ mask, float* __restrict__ out) {
  __shared__ float red[256];
  __shared__ float AffA[128];
  __shared__ float AffB[128];
  const int t = threadIdx.x, bx = blockIdx.x;
  const int b = bx >> 8;

  {
    const float4* p = (const float4*)(part_in + ((size_t)b * 256 + t) * 64);
    float s0 = 0.f, s1 = 0.f, s2 = 0.f, s3 = 0.f;
#pragma unroll 8
    for (int k = 0; k < 16; ++k) {
      float4 v = p[k];
      s0 += v.x; s1 += v.y; s2 += v.z; s3 += v.w;
    }
    red[t] = (s0 + s1) + (s2 + s3);
  }
  __syncthreads();
  if (t < 128) {
    float mean = red[2 * t] * (1.f / 4096.f);
    float var = red[2 * t + 1] * (1.f / 4096.f) - mean * mean;
    float a = gamma[t] * rsqrtf(var + 1e-3f);
    AffA[t] = a;
    AffB[t] = beta[t] - mean * a;
  }
  __syncthreads();

  const int idx = bx * 256 + t;
  const int g = idx & 15;
  const int pixel = idx >> 4;
  const int c0 = g * 8;
  uint4 v = *(const uint4*)(c2v + (size_t)pixel * CH + c0);
  const float* wp_ = wy + (size_t)pixel * CH + c0;
  float4 w0 = *(const float4*)wp_, w1 = *(const float4*)(wp_ + 4);
  float wv[8] = {w0.x, w0.y, w0.z, w0.w, w1.x, w1.y, w1.z, w1.w};
  const unsigned* vw = (const unsigned*)&v;
  float o[8];
#pragma unroll
  for (int q = 0; q < 8; ++q) {
    float cv = bf2f((q & 1) ? (vw[q >> 1] >> 16) : (vw[q >> 1] & 0xffffu));
    o[q] = wv[q] + fmaf(AffA[c0 + q], cv, AffB[c0 + q]);
  }
  const float m = maskval(mask[pixel]);
  const float* xp = x + (size_t)pixel * CH + c0;
  float4 x0 = *(const float4*)xp, x1 = *(const float4*)(xp + 4);
  float xv[8] = {x0.x, x0.y, x0.z, x0.w, x1.x, x1.y, x1.z, x1.w};
  float* op = out + (size_t)pixel * CH + c0;
  float r[8];
#pragma unroll
  for (int q = 0; q < 8; ++q) r[q] = m * xv[q] + (1.f - m) * o[q];
  *(float4*)op = make_float4(r[0], r[1], r[2], r[3]);
  *(float4*)(op + 4) = make_float4(r[4], r[5], r[6], r[7]);
}

// ================================================================ launch
extern "C" void kernel_launch(void* const* d_in, const int* in_sizes, int n_in,
                              void* d_out, int out_size, void* d_ws, size_t ws_size,
                              hipStream_t stream) {
  (void)in_sizes; (void)n_in; (void)out_size; (void)ws_size;
  const float* x    = (const float*)d_in[0];
  const float* mask = (const float*)d_in[1];
  const float* wg   = (const float*)d_in[2];
  const float* bg   = (const float*)d_in[3];
  const float* wt   = (const float*)d_in[4];
  const float* bt   = (const float*)d_in[5];
  const float* wp   = (const float*)d_in[6];
  const float* bp   = (const float*)d_in[7];
  const float* ww   = (const float*)d_in[8];
  const float* bw   = (const float*)d_in[9];
  const float* rw1  = (const float*)d_in[10];
  const float* rb1  = (const float*)d_in[11];
  const float* rg1  = (const float*)d_in[12];
  const float* rbe1 = (const float*)d_in[13];
  const float* rw2  = (const float*)d_in[14];
  const float* rb2  = (const float*)d_in[15];
  const float* rg2  = (const float*)d_in[16];
  const float* rbe2 = (const float*)d_in[17];
  float* out = (float*)d_out;

  char* W = (char*)d_ws;
  unsigned short* wfrag = (unsigned short*)W;                     // 58*32 KB = 1.81 MB
  char* base = W + 2097152;
  unsigned short* thb   = (unsigned short*)(base);                // 2 MB
  unsigned short* phb   = (unsigned short*)(base + 2097152);      // 2 MB
  unsigned short* vtb   = (unsigned short*)(base + 2 * 2097152);  // 2 MB
  float*          partL = (float*)(base + 3 * 2097152);           // 256 KB
  unsigned short* partO = (unsigned short*)(base + 3 * 2097152 + 262144);  // 16 MB
  // aliases over dead regions
  float*          wy0   = (float*)(base);                          // 4 MB over thb+phb
  unsigned short* wyb   = (unsigned short*)(base + 2 * 2097152);   // 2 MB over vtb
  unsigned short* c1    = partO;                                   // 2 MB
  unsigned short* c2    = (unsigned short*)((char*)partO + 2097152);       // 2 MB
  float*          partA = (float*)((char*)partO + 2 * 2097152);    // 128 KB used
  float*          partB = (float*)((char*)partO + 2 * 2097152 + 262144);   // 128 KB used
  float*          wy1   = (float*)((char*)partO + 5 * 1048576);    // 4 MB

  k_prepw<<<232, 256, 0, stream>>>(rw1, rw2, wt, wp, wg, ww, wfrag);
  k_proj3<<<128, 256, 0, stream>>>(x, mask, wfrag, bt, bp, bg, thb, phb, vtb);
  k_attn<<<512, 256, 0, stream>>>(thb, phb, vtb, partO, partL);
  k_gemmW<<<128, 256, 0, stream>>>(partO, partL, wfrag, bw, wy0, wyb);

  const unsigned short* wf1_0 = wfrag;
  const unsigned short* wf2_0 = wfrag + (size_t)1 * 9 * 16384;
  const unsigned short* wf1_1 = wfrag + (size_t)2 * 9 * 16384;
  const unsigned short* wf2_1 = wfrag + (size_t)3 * 9 * 16384;
  const unsigned short* wf1_2 = wfrag + (size_t)4 * 9 * 16384;
  const unsigned short* wf2_2 = wfrag + (size_t)5 * 9 * 16384;

  // block 0
  k_conv<0><<<256, 256, 0, stream>>>(wyb, wf1_0, rb1, nullptr, nullptr, nullptr,
                                     c1, partA, nullptr, nullptr);
  k_conv<1><<<256, 256, 0, stream>>>(c1, wf2_0, rb2, partA, rg1, rbe1,
                                     c2, partB, nullptr, nullptr);
  // block 1 (conv1 fuses residual(0): wy0 -> wy1)
  k_conv<2><<<256, 256, 0, stream>>>(c2, wf1_1, rb1 + 128, partB, rg2, rbe2,
                                     c1, partA, wy0, wy1);
  k_conv<1><<<256, 256, 0, stream>>>(c1, wf2_1, rb2 + 128, partA, rg1 + 128,
                                     rbe1 + 128, c2, partB, nullptr, nullptr);
  // block 2 (conv1 fuses residual(1): wy1 -> wy0)
  k_conv<2><<<256, 256, 0, stream>>>(c2, wf1_2, rb1 + 256, partB, rg2 + 128,
                                     rbe2 + 128, c1, partA, wy1, wy0);
  k_conv<1><<<256, 256, 0, stream>>>(c1, wf2_2, rb2 + 256, partA, rg1 + 256,
                                     rbe1 + 256, c2, partB, nullptr, nullptr);
  // final residual(2) + blend
  k_residual_final<<<512, 256, 0, stream>>>(c2, partB, rg2 + 256, rbe2 + 256,
                                            wy0, x, mask, out);
}

// Round 14
// 138.458 us; speedup vs baseline: 1.1275x; 1.1275x over previous
//
#include <hip/hip_runtime.h>
#include <math.h>

constexpr int NB = 2;           // batch
constexpr int IMG = 64;         // H == W
constexpr int CH = 128;         // channels
constexpr int NT = IMG * IMG;   // 4096 tokens per batch
constexpr int ATT_KSPLIT = 8;
constexpr int KPS = NT / ATT_KSPLIT;  // 512 keys per split

typedef __bf16 bf16x8 __attribute__((ext_vector_type(8)));
typedef float f32x4 __attribute__((ext_vector_type(4)));

__device__ __forceinline__ unsigned f2bf(float x) {  // RNE float->bf16 bits
  unsigned u = __float_as_uint(x);
  return (u + 0x7fffu + ((u >> 16) & 1u)) >> 16;
}
__device__ __forceinline__ float bf2f(unsigned h) {
  return __uint_as_float(h << 16);
}
__device__ __forceinline__ float maskval(float mk) {
  float mm = mk > 0.f ? 0.f : mk;
  return (1.f - mm) * (1.f - mk);
}

// ---------------------------------------------------------------- weight prep (sliced, 232 blocks)
__global__ __launch_bounds__(256) void k_prepw(
    const float* __restrict__ rw1, const float* __restrict__ rw2,
    const float* __restrict__ wt_, const float* __restrict__ wp_,
    const float* __restrict__ wg_, const float* __restrict__ ww_,
    unsigned short* __restrict__ wfrag) {
  __shared__ float Ws[32][132];
  const int t = threadIdx.x;
  const int tile = blockIdx.x >> 2, slice = blockIdx.x & 3;
  const float* src;
  if (tile < 54) {
    int i2 = tile / 9, tap = tile - i2 * 9;
    int blk = i2 >> 1;
    src = ((i2 & 1) ? rw2 : rw1) + ((size_t)blk * 9 + tap) * 16384;
  } else {
    src = tile == 54 ? wt_ : tile == 55 ? wp_ : tile == 56 ? wg_ : ww_;
  }
#pragma unroll
  for (int k = 0; k < 4; ++k) {
    int i4 = t + 256 * k;
    int row = i4 >> 5, c4 = (i4 & 31) << 2;
    *(float4*)&Ws[row][c4] =
        *(const float4*)(src + (size_t)(slice * 32 + row) * 128 + c4);
  }
  __syncthreads();
  unsigned short* dst = wfrag + (size_t)tile * 16384;
#pragma unroll
  for (int i = 0; i < 2; ++i) {
    int it = t + 256 * i;  // 0..511: cotile*64 + lane
    int cotile = it >> 6, lane = it & 63;
    int lg = lane >> 4, lc = lane & 15;
    int co = cotile * 16 + lc, r0 = lg * 8;  // local ci row
    unsigned u0 = f2bf(Ws[r0 + 0][co]) | (f2bf(Ws[r0 + 1][co]) << 16);
    unsigned u1 = f2bf(Ws[r0 + 2][co]) | (f2bf(Ws[r0 + 3][co]) << 16);
    unsigned u2 = f2bf(Ws[r0 + 4][co]) | (f2bf(Ws[r0 + 5][co]) << 16);
    unsigned u3 = f2bf(Ws[r0 + 6][co]) | (f2bf(Ws[r0 + 7][co]) << 16);
    int idx = cotile * 256 + slice * 64 + lane;
    *(uint4*)(dst + (size_t)idx * 8) = make_uint4(u0, u1, u2, u3);
  }
}

// ---------------------------------------------------------------- fused projections (round-5 form)
__global__ __launch_bounds__(256) void k_proj3(
    const float* __restrict__ x, const float* __restrict__ mask,
    const unsigned short* __restrict__ wf, const float* __restrict__ bt_,
    const float* __restrict__ bp_, const float* __restrict__ bg_,
    unsigned short* __restrict__ thb, unsigned short* __restrict__ phb,
    unsigned short* __restrict__ vtb) {
  __shared__ __align__(16) unsigned short Al[64 * 136];
  __shared__ __align__(16) unsigned short Tl[64 * 136];
  const int t = threadIdx.x, r0 = blockIdx.x * 64, b = r0 >> 12;

#pragma unroll
  for (int k = 0; k < 4; ++k) {
    int it = t + 256 * k;
    int row = it >> 4, g = it & 15;
    const float* s = x + (size_t)(r0 + row) * 128 + g * 8;
    float4 v0 = *(const float4*)s, v1 = *(const float4*)(s + 4);
    uint4 pk;
    pk.x = f2bf(v0.x) | (f2bf(v0.y) << 16);
    pk.y = f2bf(v0.z) | (f2bf(v0.w) << 16);
    pk.z = f2bf(v1.x) | (f2bf(v1.y) << 16);
    pk.w = f2bf(v1.z) | (f2bf(v1.w) << 16);
    *(uint4*)&Al[row * 136 + g * 8] = pk;
  }
  __syncthreads();

  const int w = t >> 6, lane = t & 63, lg = lane >> 4, lc = lane & 15;
  const int mw = w & 1, nw = w >> 1;
#pragma unroll
  for (int mat = 0; mat < 3; ++mat) {
    f32x4 acc[2][4];
#pragma unroll
    for (int m = 0; m < 2; ++m)
#pragma unroll
      for (int n = 0; n < 4; ++n)
#pragma unroll
        for (int r = 0; r < 4; ++r) acc[m][n][r] = 0.f;
    const unsigned short* wb =
        wf + (size_t)(54 + mat) * 16384 + (size_t)(nw * 4) * 2048 + lane * 8;
#pragma unroll
    for (int k = 0; k < 4; ++k) {
      bf16x8 a0 = *(const bf16x8*)&Al[(mw * 32 + lc) * 136 + k * 32 + lg * 8];
      bf16x8 a1 = *(const bf16x8*)&Al[(mw * 32 + 16 + lc) * 136 + k * 32 + lg * 8];
#pragma unroll
      for (int n = 0; n < 4; ++n) {
        bf16x8 bfr = *(const bf16x8*)(wb + n * 2048 + k * 512);
        acc[0][n] = __builtin_amdgcn_mfma_f32_16x16x32_bf16(a0, bfr, acc[0][n], 0, 0, 0);
        acc[1][n] = __builtin_amdgcn_mfma_f32_16x16x32_bf16(a1, bfr, acc[1][n], 0, 0, 0);
      }
    }
    const float* bs = mat == 0 ? bt_ : mat == 1 ? bp_ : bg_;
    float bbv[4];
#pragma unroll
    for (int n = 0; n < 4; ++n) bbv[n] = bs[nw * 64 + n * 16 + lc];

    if (mat < 2) {
      unsigned short* ob = mat == 0 ? thb : phb;
#pragma unroll
      for (int n = 0; n < 4; ++n) {
        int col = nw * 64 + n * 16 + lc;
#pragma unroll
        for (int m = 0; m < 2; ++m)
#pragma unroll
          for (int r = 0; r < 4; ++r) {
            int row = r0 + mw * 32 + m * 16 + lg * 4 + r;
            ob[(size_t)row * 128 + col] = (unsigned short)f2bf(acc[m][n][r] + bbv[n]);
          }
      }
    } else {
#pragma unroll
      for (int m = 0; m < 2; ++m)
#pragma unroll
        for (int r = 0; r < 4; ++r) {
          int rl = mw * 32 + m * 16 + lg * 4 + r;
          float mvv = maskval(mask[r0 + rl]);
#pragma unroll
          for (int n = 0; n < 4; ++n) {
            int col = nw * 64 + n * 16 + lc;
            Tl[rl * 136 + col] = (unsigned short)f2bf((acc[m][n][r] + bbv[n]) * mvv);
          }
        }
      __syncthreads();
      const int c = t >> 1, h = t & 1;
      unsigned buf[16];
#pragma unroll
      for (int j = 0; j < 16; ++j)
        buf[j] = (unsigned)Tl[(h * 32 + 2 * j) * 136 + c] |
                 ((unsigned)Tl[(h * 32 + 2 * j + 1) * 136 + c] << 16);
      const int key0 = r0 & (NT - 1);
      unsigned short* dst = vtb + ((size_t)b * CH + c) * NT + key0 + h * 32;
      uint4* d4 = (uint4*)dst;
#pragma unroll
      for (int q = 0; q < 4; ++q)
        d4[q] = make_uint4(buf[4 * q], buf[4 * q + 1], buf[4 * q + 2], buf[4 * q + 3]);
    }
  }
}

// ---------------------------------------------------------------- flash attention (round-12 exact)
__global__ __launch_bounds__(256, 2) void k_attn(
    const unsigned short* __restrict__ theta, const unsigned short* __restrict__ phi,
    const unsigned short* __restrict__ vt, unsigned short* __restrict__ partO,
    float* __restrict__ partL) {
  __shared__ __align__(16) unsigned short Klds[64][136];
  __shared__ __align__(16) unsigned short Vtlds[128][72];
  __shared__ __align__(16) unsigned short Plds[4][32][72];

  const int t = threadIdx.x;
  const int bx = blockIdx.x;
  const int qt = bx & 31;
  const int ks = (bx >> 5) & 7;
  const int b = bx >> 8;
  const int w = t >> 6;
  const int lane = t & 63;
  const int lg = lane >> 4;
  const int lc = lane & 15;
  const int q0 = qt * 128 + w * 32;

  const unsigned short* thB = theta + (size_t)b * NT * CH;
  const unsigned short* phB = phi + (size_t)b * NT * CH;
  const unsigned short* vtB = vt + (size_t)b * CH * NT;

  bf16x8 qf[2][4];
#pragma unroll
  for (int q2 = 0; q2 < 2; ++q2)
#pragma unroll
    for (int k = 0; k < 4; ++k)
      qf[q2][k] = *(const bf16x8*)(thB + (size_t)(q0 + q2 * 16 + lc) * CH + k * 32 + lg * 8);

  f32x4 oacc[2][8];
#pragma unroll
  for (int q2 = 0; q2 < 2; ++q2)
#pragma unroll
    for (int c = 0; c < 8; ++c)
#pragma unroll
      for (int r = 0; r < 4; ++r) oacc[q2][c][r] = 0.f;
  float lsum[2][4] = {{0.f, 0.f, 0.f, 0.f}, {0.f, 0.f, 0.f, 0.f}};

  for (int kt = 0; kt < KPS; kt += 64) {
    const int key0 = ks * KPS + kt;
    __syncthreads();
#pragma unroll
    for (int i = 0; i < 4; ++i) {
      int idx = t + 256 * i;
      int row = idx >> 4, c8 = (idx & 15) * 8;
      *(uint4*)&Klds[row][c8] = *(const uint4*)(phB + (size_t)(key0 + row) * CH + c8);
      int rowv = idx >> 3, k8 = (idx & 7) * 8;
      *(uint4*)&Vtlds[rowv][k8] = *(const uint4*)(vtB + (size_t)rowv * NT + key0 + k8);
    }
    __syncthreads();

#pragma unroll
    for (int col = 0; col < 4; ++col) {
      bf16x8 kf[4];
#pragma unroll
      for (int k = 0; k < 4; ++k)
        kf[k] = *(const bf16x8*)&Klds[col * 16 + lc][k * 32 + lg * 8];
      f32x4 s0, s1;
#pragma unroll
      for (int r = 0; r < 4; ++r) { s0[r] = 0.f; s1[r] = 0.f; }
#pragma unroll
      for (int k = 0; k < 4; ++k) {
        s0 = __builtin_amdgcn_mfma_f32_16x16x32_bf16(qf[0][k], kf[k], s0, 0, 0, 0);
        s1 = __builtin_amdgcn_mfma_f32_16x16x32_bf16(qf[1][k], kf[k], s1, 0, 0, 0);
      }
#pragma unroll
      for (int r = 0; r < 4; ++r) {
        float p0 = __expf(s0[r]);
        lsum[0][r] += p0;
        Plds[w][lg * 4 + r][col * 16 + lc] = (unsigned short)f2bf(p0);
        float p1 = __expf(s1[r]);
        lsum[1][r] += p1;
        Plds[w][16 + lg * 4 + r][col * 16 + lc] = (unsigned short)f2bf(p1);
      }
    }

#pragma unroll
    for (int kp = 0; kp < 2; ++kp) {
      bf16x8 pa0 = *(const bf16x8*)&Plds[w][lc][kp * 32 + lg * 8];
      bf16x8 pa1 = *(const bf16x8*)&Plds[w][16 + lc][kp * 32 + lg * 8];
#pragma unroll
      for (int col = 0; col < 8; ++col) {
        bf16x8 vf = *(const bf16x8*)&Vtlds[col * 16 + lc][kp * 32 + lg * 8];
        oacc[0][col] = __builtin_amdgcn_mfma_f32_16x16x32_bf16(pa0, vf, oacc[0][col], 0, 0, 0);
        oacc[1][col] = __builtin_amdgcn_mfma_f32_16x16x32_bf16(pa1, vf, oacc[1][col], 0, 0, 0);
      }
    }
  }

#pragma unroll
  for (int off = 1; off < 16; off <<= 1)
#pragma unroll
    for (int q2 = 0; q2 < 2; ++q2)
#pragma unroll
      for (int r = 0; r < 4; ++r) lsum[q2][r] += __shfl_xor(lsum[q2][r], off);

  const size_t obase = ((size_t)ks * NB + b) * NT;
#pragma unroll
  for (int q2 = 0; q2 < 2; ++q2) {
#pragma unroll
    for (int col = 0; col < 8; ++col)
#pragma unroll
      for (int r = 0; r < 4; ++r) {
        int row = q0 + q2 * 16 + lg * 4 + r;
        partO[(obase + row) * CH + col * 16 + lc] = (unsigned short)f2bf(oacc[q2][col][r]);
      }
    if (lc == 0) {
#pragma unroll
      for (int r = 0; r < 4; ++r)
        partL[obase + q0 + q2 * 16 + lg * 4 + r] = lsum[q2][r];
    }
  }
}

// ---------------------------------------------------------------- W gemm + combine (round-5 form)
__global__ __launch_bounds__(256) void k_gemmW(
    const unsigned short* __restrict__ partO, const float* __restrict__ partL,
    const unsigned short* __restrict__ wf, const float* __restrict__ bias,
    float* __restrict__ wy, unsigned short* __restrict__ wyb) {
  __shared__ __align__(16) unsigned short Al[64 * 136];
  __shared__ float linv[64];
  const int t = threadIdx.x, r0 = blockIdx.x * 64;

  if (t < 64) {
    float l = 0.f;
#pragma unroll
    for (int ks = 0; ks < ATT_KSPLIT; ++ks) l += partL[(size_t)ks * 8192 + r0 + t];
    linv[t] = 1.f / l;
  }
  __syncthreads();

#pragma unroll
  for (int i = 0; i < 4; ++i) {
    int it = t + 256 * i;
    int row = it >> 4, g = it & 15;
    float a[8] = {0.f, 0.f, 0.f, 0.f, 0.f, 0.f, 0.f, 0.f};
#pragma unroll
    for (int ks = 0; ks < ATT_KSPLIT; ++ks) {
      uint4 u = *(const uint4*)(partO + ((size_t)ks * 8192 + r0 + row) * 128 + g * 8);
      const unsigned* uw = (const unsigned*)&u;
#pragma unroll
      for (int q = 0; q < 4; ++q) {
        a[2 * q] += bf2f(uw[q] & 0xffffu);
        a[2 * q + 1] += bf2f(uw[q] >> 16);
      }
    }
    float s = linv[row];
    uint4 pk;
    pk.x = f2bf(a[0] * s) | (f2bf(a[1] * s) << 16);
    pk.y = f2bf(a[2] * s) | (f2bf(a[3] * s) << 16);
    pk.z = f2bf(a[4] * s) | (f2bf(a[5] * s) << 16);
    pk.w = f2bf(a[6] * s) | (f2bf(a[7] * s) << 16);
    *(uint4*)&Al[row * 136 + g * 8] = pk;
  }
  __syncthreads();

  const int w = t >> 6, lane = t & 63, lg = lane >> 4, lc = lane & 15;
  const int mw = w & 1, nw = w >> 1;
  f32x4 acc[2][4];
#pragma unroll
  for (int m = 0; m < 2; ++m)
#pragma unroll
    for (int n = 0; n < 4; ++n)
#pragma unroll
      for (int r = 0; r < 4; ++r) acc[m][n][r] = 0.f;
  const unsigned short* wb =
      wf + (size_t)57 * 16384 + (size_t)(nw * 4) * 2048 + lane * 8;
#pragma unroll
  for (int k = 0; k < 4; ++k) {
    bf16x8 a0 = *(const bf16x8*)&Al[(mw * 32 + lc) * 136 + k * 32 + lg * 8];
    bf16x8 a1 = *(const bf16x8*)&Al[(mw * 32 + 16 + lc) * 136 + k * 32 + lg * 8];
#pragma unroll
    for (int n = 0; n < 4; ++n) {
      bf16x8 bfr = *(const bf16x8*)(wb + n * 2048 + k * 512);
      acc[0][n] = __builtin_amdgcn_mfma_f32_16x16x32_bf16(a0, bfr, acc[0][n], 0, 0, 0);
      acc[1][n] = __builtin_amdgcn_mfma_f32_16x16x32_bf16(a1, bfr, acc[1][n], 0, 0, 0);
    }
  }
#pragma unroll
  for (int n = 0; n < 4; ++n) {
    int col = nw * 64 + n * 16 + lc;
    float bb = bias[col];
#pragma unroll
    for (int m = 0; m < 2; ++m)
#pragma unroll
      for (int r = 0; r < 4; ++r) {
        int row = r0 + mw * 32 + m * 16 + lg * 4 + r;
        float v = acc[m][n][r] + bb;
        wy[(size_t)row * 128 + col] = v;
        wyb[(size_t)row * 128 + col] = (unsigned short)f2bf(v);
      }
  }
}

// ---------------------------------------------------------------- 3x3 reflect conv (bf16 MFMA)
// 512-thread blocks, grid 256. MODE 0: plain bf16 input. MODE 1: relu(IN(input)).
// MODE 2: input = wy_in + IN(c2) (fused residual); owner row writes f32 result to wy_out.
template <int MODE>
__global__ __launch_bounds__(512, 2) void k_conv(
    const unsigned short* __restrict__ act, const unsigned short* __restrict__ wf,
    const float* __restrict__ bias, const float* __restrict__ part_in,
    const float* __restrict__ gamma, const float* __restrict__ beta,
    unsigned short* __restrict__ outc, float* __restrict__ part_out,
    const float* __restrict__ wy_in, float* __restrict__ wy_out) {
  __shared__ unsigned short Alds[3][34 * 136];
  __shared__ float red[256];
  __shared__ float Aff[2][128];

  const int t = threadIdx.x, bx = blockIdx.x;
  const int xh = bx & 1, y = (bx >> 1) & 63, b = bx >> 7;
  const int w = t >> 6, lane = t & 63, lg = lane >> 4, lc = lane & 15;
  const int x0 = xh * 32;
  const int coT = w;  // 8 waves cover all 8 co-tiles

  if constexpr (MODE >= 1) {
    if (t < 256) {
      const float4* p = (const float4*)(part_in + ((size_t)b * 256 + t) * 128);
      float s0 = 0.f, s1 = 0.f, s2 = 0.f, s3 = 0.f;
#pragma unroll 8
      for (int k = 0; k < 32; ++k) {
        float4 v = p[k];
        s0 += v.x; s1 += v.y; s2 += v.z; s3 += v.w;
      }
      red[t] = (s0 + s1) + (s2 + s3);
    }
    __syncthreads();
    if (t < 128) {
      float mean = red[2 * t] * (1.f / 4096.f);
      float var = red[2 * t + 1] * (1.f / 4096.f) - mean * mean;
      float a = gamma[t] * rsqrtf(var + 1e-3f);
      Aff[0][t] = a;
      Aff[1][t] = beta[t] - mean * a;
    }
    __syncthreads();
  }

  const unsigned short* actB = act + (size_t)b * NT * CH;
#pragma unroll
  for (int i = 0; i < 4; ++i) {
    int it = t + 512 * i;
    if (it < 1632) {
      int r = it / 544, rem = it - r * 544;
      int px = rem >> 4, g = rem & 15;
      int sy = y - 1 + r;
      sy = sy < 0 ? 1 : (sy > 63 ? 62 : sy);
      int sx = x0 - 1 + px;
      sx = sx < 0 ? 1 : (sx > 63 ? 62 : sx);
      const int lpix = sy * 64 + sx;
      uint4 v = *(const uint4*)(actB + (size_t)lpix * CH + g * 8);
      if constexpr (MODE == 1) {
        int c0 = g * 8;
        unsigned* vw = (unsigned*)&v;
#pragma unroll
        for (int q = 0; q < 4; ++q) {
          float v0 = bf2f(vw[q] & 0xffffu), v1 = bf2f(vw[q] >> 16);
          v0 = fmaxf(0.f, fmaf(Aff[0][c0 + 2 * q], v0, Aff[1][c0 + 2 * q]));
          v1 = fmaxf(0.f, fmaf(Aff[0][c0 + 2 * q + 1], v1, Aff[1][c0 + 2 * q + 1]));
          vw[q] = f2bf(v0) | (f2bf(v1) << 16);
        }
      } else if constexpr (MODE == 2) {
        int c0 = g * 8;
        const size_t gpix = (size_t)b * NT + lpix;
        const float* wpin = wy_in + gpix * CH + c0;
        float4 w0 = *(const float4*)wpin, w1 = *(const float4*)(wpin + 4);
        float wv[8] = {w0.x, w0.y, w0.z, w0.w, w1.x, w1.y, w1.z, w1.w};
        const unsigned* vw = (const unsigned*)&v;
        float o[8];
#pragma unroll
        for (int q = 0; q < 8; ++q) {
          float cv = bf2f((q & 1) ? (vw[q >> 1] >> 16) : (vw[q >> 1] & 0xffffu));
          o[q] = wv[q] + fmaf(Aff[0][c0 + q], cv, Aff[1][c0 + q]);
        }
        if (r == 1 && px >= 1 && px < 33) {  // own row, interior: write residual f32
          float* wpo = wy_out + gpix * CH + c0;
          *(float4*)wpo = make_float4(o[0], o[1], o[2], o[3]);
          *(float4*)(wpo + 4) = make_float4(o[4], o[5], o[6], o[7]);
        }
        uint4 pk;
        pk.x = f2bf(o[0]) | (f2bf(o[1]) << 16);
        pk.y = f2bf(o[2]) | (f2bf(o[3]) << 16);
        pk.z = f2bf(o[4]) | (f2bf(o[5]) << 16);
        pk.w = f2bf(o[6]) | (f2bf(o[7]) << 16);
        v = pk;
      }
      *(uint4*)&Alds[r][px * 136 + g * 8] = v;
    }
  }
  __syncthreads();

  f32x4 acc[2];
#pragma unroll
  for (int m = 0; m < 2; ++m)
#pragma unroll
    for (int r = 0; r < 4; ++r) acc[m][r] = 0.f;

  const unsigned short* wbase = wf + (size_t)coT * 2048 + lane * 8;
  bf16x8 wc[4], wn[4];
#pragma unroll
  for (int k = 0; k < 4; ++k) wc[k] = *(const bf16x8*)(wbase + k * 512);
#pragma unroll
  for (int tap = 0; tap < 9; ++tap) {
    const int dy = tap / 3, dx = tap - dy * 3;
    if (tap < 8) {
#pragma unroll
      for (int k = 0; k < 4; ++k)
        wn[k] = *(const bf16x8*)(wbase + (size_t)(tap + 1) * 16384 + k * 512);
    }
#pragma unroll
    for (int k = 0; k < 4; ++k) {
      bf16x8 a0 = *(const bf16x8*)&Alds[dy][(dx + lc) * 136 + k * 32 + lg * 8];
      bf16x8 a1 = *(const bf16x8*)&Alds[dy][(dx + 16 + lc) * 136 + k * 32 + lg * 8];
      acc[0] = __builtin_amdgcn_mfma_f32_16x16x32_bf16(a0, wc[k], acc[0], 0, 0, 0);
      acc[1] = __builtin_amdgcn_mfma_f32_16x16x32_bf16(a1, wc[k], acc[1], 0, 0, 0);
    }
#pragma unroll
    for (int k = 0; k < 4; ++k) wc[k] = wn[k];
  }

  const int col = coT * 16 + lc;
  const float bs = bias[col];
  float sum = 0.f, sq = 0.f;
  unsigned short* outB = outc + (size_t)(b * NT + y * 64 + x0) * CH;
#pragma unroll
  for (int m = 0; m < 2; ++m)
#pragma unroll
    for (int r = 0; r < 4; ++r) {
      float v = acc[m][r] + bs;
      int px = m * 16 + lg * 4 + r;
      outB[(size_t)px * CH + col] = (unsigned short)f2bf(v);
      sum += v;
      sq = fmaf(v, v, sq);
    }
  sum += __shfl_xor(sum, 16);
  sum += __shfl_xor(sum, 32);
  sq += __shfl_xor(sq, 16);
  sq += __shfl_xor(sq, 32);
  if (lg == 0) {
    const int pg = y * 2 + xh;
    part_out[((size_t)(b * 128 + col) * 2 + 0) * 128 + pg] = sum;
    part_out[((size_t)(b * 128 + col) * 2 + 1) * 128 + pg] = sq;
  }
}

// ---------------------------------------------------------------- final residual (+stats reduce, +blend)
__global__ __launch_bounds__(256) void k_residual_final(
    const unsigned short* __restrict__ c2v, const float* __restrict__ part_in,
    const float* __restrict__ gamma, const float* __restrict__ beta,
    const float* __restrict__ wy, const float* __restrict__ x,
    const float* __restrict__ mask, float* __restrict__ out) {
  __shared__ float red[256];
  __shared__ float AffA[128];
  __shared__ float AffB[128];
  const int t = threadIdx.x, bx = blockIdx.x;
  const int b = bx >> 8;

  {
    const float4* p = (const float4*)(part_in + ((size_t)b * 256 + t) * 128);
    float s0 = 0.f, s1 = 0.f, s2 = 0.f, s3 = 0.f;
#pragma unroll 8
    for (int k = 0; k < 32; ++k) {
      float4 v = p[k];
      s0 += v.x; s1 += v.y; s2 += v.z; s3 += v.w;
    }
    red[t] = (s0 + s1) + (s2 + s3);
  }
  __syncthreads();
  if (t < 128) {
    float mean = red[2 * t] * (1.f / 4096.f);
    float var = red[2 * t + 1] * (1.f / 4096.f) - mean * mean;
    float a = gamma[t] * rsqrtf(var + 1e-3f);
    AffA[t] = a;
    AffB[t] = beta[t] - mean * a;
  }
  __syncthreads();

  const int idx = bx * 256 + t;
  const int g = idx & 15;
  const int pixel = idx >> 4;
  const int c0 = g * 8;
  uint4 v = *(const uint4*)(c2v + (size_t)pixel * CH + c0);
  const float* wp_ = wy + (size_t)pixel * CH + c0;
  float4 w0 = *(const float4*)wp_, w1 = *(const float4*)(wp_ + 4);
  float wv[8] = {w0.x, w0.y, w0.z, w0.w, w1.x, w1.y, w1.z, w1.w};
  const unsigned* vw = (const unsigned*)&v;
  float o[8];
#pragma unroll
  for (int q = 0; q < 8; ++q) {
    float cv = bf2f((q & 1) ? (vw[q >> 1] >> 16) : (vw[q >> 1] & 0xffffu));
    o[q] = wv[q] + fmaf(AffA[c0 + q], cv, AffB[c0 + q]);
  }
  const float m = maskval(mask[pixel]);
  const float* xp = x + (size_t)pixel * CH + c0;
  float4 x0 = *(const float4*)xp, x1 = *(const float4*)(xp + 4);
  float xv[8] = {x0.x, x0.y, x0.z, x0.w, x1.x, x1.y, x1.z, x1.w};
  float* op = out + (size_t)pixel * CH + c0;
  float r[8];
#pragma unroll
  for (int q = 0; q < 8; ++q) r[q] = m * xv[q] + (1.f - m) * o[q];
  *(float4*)op = make_float4(r[0], r[1], r[2], r[3]);
  *(float4*)(op + 4) = make_float4(r[4], r[5], r[6], r[7]);
}

// ================================================================ launch
extern "C" void kernel_launch(void* const* d_in, const int* in_sizes, int n_in,
                              void* d_out, int out_size, void* d_ws, size_t ws_size,
                              hipStream_t stream) {
  (void)in_sizes; (void)n_in; (void)out_size; (void)ws_size;
  const float* x    = (const float*)d_in[0];
  const float* mask = (const float*)d_in[1];
  const float* wg   = (const float*)d_in[2];
  const float* bg   = (const float*)d_in[3];
  const float* wt   = (const float*)d_in[4];
  const float* bt   = (const float*)d_in[5];
  const float* wp   = (const float*)d_in[6];
  const float* bp   = (const float*)d_in[7];
  const float* ww   = (const float*)d_in[8];
  const float* bw   = (const float*)d_in[9];
  const float* rw1  = (const float*)d_in[10];
  const float* rb1  = (const float*)d_in[11];
  const float* rg1  = (const float*)d_in[12];
  const float* rbe1 = (const float*)d_in[13];
  const float* rw2  = (const float*)d_in[14];
  const float* rb2  = (const float*)d_in[15];
  const float* rg2  = (const float*)d_in[16];
  const float* rbe2 = (const float*)d_in[17];
  float* out = (float*)d_out;

  char* W = (char*)d_ws;
  unsigned short* wfrag = (unsigned short*)W;                     // 58*32 KB = 1.81 MB
  char* base = W + 2097152;
  unsigned short* thb   = (unsigned short*)(base);                // 2 MB
  unsigned short* phb   = (unsigned short*)(base + 2097152);      // 2 MB
  unsigned short* vtb   = (unsigned short*)(base + 2 * 2097152);  // 2 MB
  float*          partL = (float*)(base + 3 * 2097152);           // 256 KB
  unsigned short* partO = (unsigned short*)(base + 3 * 2097152 + 262144);  // 16 MB
  // aliases over dead regions
  float*          wy0   = (float*)(base);                          // 4 MB over thb+phb
  unsigned short* wyb   = (unsigned short*)(base + 2 * 2097152);   // 2 MB over vtb
  unsigned short* c1    = partO;                                   // 2 MB
  unsigned short* c2    = (unsigned short*)((char*)partO + 2097152);       // 2 MB
  float*          partA = (float*)((char*)partO + 2 * 2097152);    // 256 KB
  float*          partB = (float*)((char*)partO + 2 * 2097152 + 262144);   // 256 KB
  float*          wy1   = (float*)((char*)partO + 5 * 1048576);    // 4 MB

  k_prepw<<<232, 256, 0, stream>>>(rw1, rw2, wt, wp, wg, ww, wfrag);
  k_proj3<<<128, 256, 0, stream>>>(x, mask, wfrag, bt, bp, bg, thb, phb, vtb);
  k_attn<<<512, 256, 0, stream>>>(thb, phb, vtb, partO, partL);
  k_gemmW<<<128, 256, 0, stream>>>(partO, partL, wfrag, bw, wy0, wyb);

  const unsigned short* wf1_0 = wfrag;
  const unsigned short* wf2_0 = wfrag + (size_t)1 * 9 * 16384;
  const unsigned short* wf1_1 = wfrag + (size_t)2 * 9 * 16384;
  const unsigned short* wf2_1 = wfrag + (size_t)3 * 9 * 16384;
  const unsigned short* wf1_2 = wfrag + (size_t)4 * 9 * 16384;
  const unsigned short* wf2_2 = wfrag + (size_t)5 * 9 * 16384;

  // block 0
  k_conv<0><<<256, 512, 0, stream>>>(wyb, wf1_0, rb1, nullptr, nullptr, nullptr,
                                     c1, partA, nullptr, nullptr);
  k_conv<1><<<256, 512, 0, stream>>>(c1, wf2_0, rb2, partA, rg1, rbe1,
                                     c2, partB, nullptr, nullptr);
  // block 1 (conv1 fuses residual(0): wy0 -> wy1)
  k_conv<2><<<256, 512, 0, stream>>>(c2, wf1_1, rb1 + 128, partB, rg2, rbe2,
                                     c1, partA, wy0, wy1);
  k_conv<1><<<256, 512, 0, stream>>>(c1, wf2_1, rb2 + 128, partA, rg1 + 128,
                                     rbe1 + 128, c2, partB, nullptr, nullptr);
  // block 2 (conv1 fuses residual(1): wy1 -> wy0)
  k_conv<2><<<256, 512, 0, stream>>>(c2, wf1_2, rb1 + 256, partB, rg2 + 128,
                                     rbe2 + 128, c1, partA, wy1, wy0);
  k_conv<1><<<256, 512, 0, stream>>>(c1, wf2_2, rb2 + 256, partA, rg1 + 256,
                                     rbe1 + 256, c2, partB, nullptr, nullptr);
  // final residual(2) + blend
  k_residual_final<<<512, 256, 0, stream>>>(c2, partB, rg2 + 256, rbe2 + 256,
                                            wy0, x, mask, out);
}

// Round 15
// 133.246 us; speedup vs baseline: 1.1716x; 1.0391x over previous
//
#include <hip/hip_runtime.h>
#include <math.h>

constexpr int NB = 2;           // batch
constexpr int IMG = 64;         // H == W
constexpr int CH = 128;         // channels
constexpr int NT = IMG * IMG;   // 4096 tokens per batch
constexpr int ATT_KSPLIT = 8;
constexpr int KPS = NT / ATT_KSPLIT;  // 512 keys per split

typedef __bf16 bf16x8 __attribute__((ext_vector_type(8)));
typedef float f32x4 __attribute__((ext_vector_type(4)));

__device__ __forceinline__ unsigned f2bf(float x) {  // RNE float->bf16 bits
  unsigned u = __float_as_uint(x);
  return (u + 0x7fffu + ((u >> 16) & 1u)) >> 16;
}
__device__ __forceinline__ float bf2f(unsigned h) {
  return __uint_as_float(h << 16);
}
__device__ __forceinline__ float maskval(float mk) {
  float mm = mk > 0.f ? 0.f : mk;
  return (1.f - mm) * (1.f - mk);
}

// ---------------------------------------------------------------- weight prep (sliced, 232 blocks)
__global__ __launch_bounds__(256) void k_prepw(
    const float* __restrict__ rw1, const float* __restrict__ rw2,
    const float* __restrict__ wt_, const float* __restrict__ wp_,
    const float* __restrict__ wg_, const float* __restrict__ ww_,
    unsigned short* __restrict__ wfrag) {
  __shared__ float Ws[32][132];
  const int t = threadIdx.x;
  const int tile = blockIdx.x >> 2, slice = blockIdx.x & 3;
  const float* src;
  if (tile < 54) {
    int i2 = tile / 9, tap = tile - i2 * 9;
    int blk = i2 >> 1;
    src = ((i2 & 1) ? rw2 : rw1) + ((size_t)blk * 9 + tap) * 16384;
  } else {
    src = tile == 54 ? wt_ : tile == 55 ? wp_ : tile == 56 ? wg_ : ww_;
  }
#pragma unroll
  for (int k = 0; k < 4; ++k) {
    int i4 = t + 256 * k;
    int row = i4 >> 5, c4 = (i4 & 31) << 2;
    *(float4*)&Ws[row][c4] =
        *(const float4*)(src + (size_t)(slice * 32 + row) * 128 + c4);
  }
  __syncthreads();
  unsigned short* dst = wfrag + (size_t)tile * 16384;
#pragma unroll
  for (int i = 0; i < 2; ++i) {
    int it = t + 256 * i;  // 0..511: cotile*64 + lane
    int cotile = it >> 6, lane = it & 63;
    int lg = lane >> 4, lc = lane & 15;
    int co = cotile * 16 + lc, r0 = lg * 8;  // local ci row
    unsigned u0 = f2bf(Ws[r0 + 0][co]) | (f2bf(Ws[r0 + 1][co]) << 16);
    unsigned u1 = f2bf(Ws[r0 + 2][co]) | (f2bf(Ws[r0 + 3][co]) << 16);
    unsigned u2 = f2bf(Ws[r0 + 4][co]) | (f2bf(Ws[r0 + 5][co]) << 16);
    unsigned u3 = f2bf(Ws[r0 + 6][co]) | (f2bf(Ws[r0 + 7][co]) << 16);
    int idx = cotile * 256 + slice * 64 + lane;
    *(uint4*)(dst + (size_t)idx * 8) = make_uint4(u0, u1, u2, u3);
  }
}

// ---------------------------------------------------------------- fused projections (round-5 form)
__global__ __launch_bounds__(256) void k_proj3(
    const float* __restrict__ x, const float* __restrict__ mask,
    const unsigned short* __restrict__ wf, const float* __restrict__ bt_,
    const float* __restrict__ bp_, const float* __restrict__ bg_,
    unsigned short* __restrict__ thb, unsigned short* __restrict__ phb,
    unsigned short* __restrict__ vtb) {
  __shared__ __align__(16) unsigned short Al[64 * 136];
  __shared__ __align__(16) unsigned short Tl[64 * 136];
  const int t = threadIdx.x, r0 = blockIdx.x * 64, b = r0 >> 12;

#pragma unroll
  for (int k = 0; k < 4; ++k) {
    int it = t + 256 * k;
    int row = it >> 4, g = it & 15;
    const float* s = x + (size_t)(r0 + row) * 128 + g * 8;
    float4 v0 = *(const float4*)s, v1 = *(const float4*)(s + 4);
    uint4 pk;
    pk.x = f2bf(v0.x) | (f2bf(v0.y) << 16);
    pk.y = f2bf(v0.z) | (f2bf(v0.w) << 16);
    pk.z = f2bf(v1.x) | (f2bf(v1.y) << 16);
    pk.w = f2bf(v1.z) | (f2bf(v1.w) << 16);
    *(uint4*)&Al[row * 136 + g * 8] = pk;
  }
  __syncthreads();

  const int w = t >> 6, lane = t & 63, lg = lane >> 4, lc = lane & 15;
  const int mw = w & 1, nw = w >> 1;
#pragma unroll
  for (int mat = 0; mat < 3; ++mat) {
    f32x4 acc[2][4];
#pragma unroll
    for (int m = 0; m < 2; ++m)
#pragma unroll
      for (int n = 0; n < 4; ++n)
#pragma unroll
        for (int r = 0; r < 4; ++r) acc[m][n][r] = 0.f;
    const unsigned short* wb =
        wf + (size_t)(54 + mat) * 16384 + (size_t)(nw * 4) * 2048 + lane * 8;
#pragma unroll
    for (int k = 0; k < 4; ++k) {
      bf16x8 a0 = *(const bf16x8*)&Al[(mw * 32 + lc) * 136 + k * 32 + lg * 8];
      bf16x8 a1 = *(const bf16x8*)&Al[(mw * 32 + 16 + lc) * 136 + k * 32 + lg * 8];
#pragma unroll
      for (int n = 0; n < 4; ++n) {
        bf16x8 bfr = *(const bf16x8*)(wb + n * 2048 + k * 512);
        acc[0][n] = __builtin_amdgcn_mfma_f32_16x16x32_bf16(a0, bfr, acc[0][n], 0, 0, 0);
        acc[1][n] = __builtin_amdgcn_mfma_f32_16x16x32_bf16(a1, bfr, acc[1][n], 0, 0, 0);
      }
    }
    const float* bs = mat == 0 ? bt_ : mat == 1 ? bp_ : bg_;
    float bbv[4];
#pragma unroll
    for (int n = 0; n < 4; ++n) bbv[n] = bs[nw * 64 + n * 16 + lc];

    if (mat < 2) {
      unsigned short* ob = mat == 0 ? thb : phb;
#pragma unroll
      for (int n = 0; n < 4; ++n) {
        int col = nw * 64 + n * 16 + lc;
#pragma unroll
        for (int m = 0; m < 2; ++m)
#pragma unroll
          for (int r = 0; r < 4; ++r) {
            int row = r0 + mw * 32 + m * 16 + lg * 4 + r;
            ob[(size_t)row * 128 + col] = (unsigned short)f2bf(acc[m][n][r] + bbv[n]);
          }
      }
    } else {
#pragma unroll
      for (int m = 0; m < 2; ++m)
#pragma unroll
        for (int r = 0; r < 4; ++r) {
          int rl = mw * 32 + m * 16 + lg * 4 + r;
          float mvv = maskval(mask[r0 + rl]);
#pragma unroll
          for (int n = 0; n < 4; ++n) {
            int col = nw * 64 + n * 16 + lc;
            Tl[rl * 136 + col] = (unsigned short)f2bf((acc[m][n][r] + bbv[n]) * mvv);
          }
        }
      __syncthreads();
      const int c = t >> 1, h = t & 1;
      unsigned buf[16];
#pragma unroll
      for (int j = 0; j < 16; ++j)
        buf[j] = (unsigned)Tl[(h * 32 + 2 * j) * 136 + c] |
                 ((unsigned)Tl[(h * 32 + 2 * j + 1) * 136 + c] << 16);
      const int key0 = r0 & (NT - 1);
      unsigned short* dst = vtb + ((size_t)b * CH + c) * NT + key0 + h * 32;
      uint4* d4 = (uint4*)dst;
#pragma unroll
      for (int q = 0; q < 4; ++q)
        d4[q] = make_uint4(buf[4 * q], buf[4 * q + 1], buf[4 * q + 2], buf[4 * q + 3]);
    }
  }
}

// ---------------------------------------------------------------- flash attention (round-12 +
// XCD-chunked block swizzle: each XCD owns a contiguous 64-block range = 2 ks-splits
// of one batch, so its private L2 holds only 512 KB of K/V instead of all 4 MB)
__global__ __launch_bounds__(256, 2) void k_attn(
    const unsigned short* __restrict__ theta, const unsigned short* __restrict__ phi,
    const unsigned short* __restrict__ vt, unsigned short* __restrict__ partO,
    float* __restrict__ partL) {
  __shared__ __align__(16) unsigned short Klds[64][136];
  __shared__ __align__(16) unsigned short Vtlds[128][72];
  __shared__ __align__(16) unsigned short Plds[4][32][72];

  const int t = threadIdx.x;
  const int bx = (blockIdx.x & 7) * 64 + (blockIdx.x >> 3);  // XCD-chunked (512%8==0)
  const int qt = bx & 31;
  const int ks = (bx >> 5) & 7;
  const int b = bx >> 8;
  const int w = t >> 6;
  const int lane = t & 63;
  const int lg = lane >> 4;
  const int lc = lane & 15;
  const int q0 = qt * 128 + w * 32;

  const unsigned short* thB = theta + (size_t)b * NT * CH;
  const unsigned short* phB = phi + (size_t)b * NT * CH;
  const unsigned short* vtB = vt + (size_t)b * CH * NT;

  bf16x8 qf[2][4];
#pragma unroll
  for (int q2 = 0; q2 < 2; ++q2)
#pragma unroll
    for (int k = 0; k < 4; ++k)
      qf[q2][k] = *(const bf16x8*)(thB + (size_t)(q0 + q2 * 16 + lc) * CH + k * 32 + lg * 8);

  f32x4 oacc[2][8];
#pragma unroll
  for (int q2 = 0; q2 < 2; ++q2)
#pragma unroll
    for (int c = 0; c < 8; ++c)
#pragma unroll
      for (int r = 0; r < 4; ++r) oacc[q2][c][r] = 0.f;
  float lsum[2][4] = {{0.f, 0.f, 0.f, 0.f}, {0.f, 0.f, 0.f, 0.f}};

  for (int kt = 0; kt < KPS; kt += 64) {
    const int key0 = ks * KPS + kt;
    __syncthreads();
#pragma unroll
    for (int i = 0; i < 4; ++i) {
      int idx = t + 256 * i;
      int row = idx >> 4, c8 = (idx & 15) * 8;
      *(uint4*)&Klds[row][c8] = *(const uint4*)(phB + (size_t)(key0 + row) * CH + c8);
      int rowv = idx >> 3, k8 = (idx & 7) * 8;
      *(uint4*)&Vtlds[rowv][k8] = *(const uint4*)(vtB + (size_t)rowv * NT + key0 + k8);
    }
    __syncthreads();

#pragma unroll
    for (int col = 0; col < 4; ++col) {
      bf16x8 kf[4];
#pragma unroll
      for (int k = 0; k < 4; ++k)
        kf[k] = *(const bf16x8*)&Klds[col * 16 + lc][k * 32 + lg * 8];
      f32x4 s0, s1;
#pragma unroll
      for (int r = 0; r < 4; ++r) { s0[r] = 0.f; s1[r] = 0.f; }
#pragma unroll
      for (int k = 0; k < 4; ++k) {
        s0 = __builtin_amdgcn_mfma_f32_16x16x32_bf16(qf[0][k], kf[k], s0, 0, 0, 0);
        s1 = __builtin_amdgcn_mfma_f32_16x16x32_bf16(qf[1][k], kf[k], s1, 0, 0, 0);
      }
#pragma unroll
      for (int r = 0; r < 4; ++r) {
        float p0 = __expf(s0[r]);
        lsum[0][r] += p0;
        Plds[w][lg * 4 + r][col * 16 + lc] = (unsigned short)f2bf(p0);
        float p1 = __expf(s1[r]);
        lsum[1][r] += p1;
        Plds[w][16 + lg * 4 + r][col * 16 + lc] = (unsigned short)f2bf(p1);
      }
    }

#pragma unroll
    for (int kp = 0; kp < 2; ++kp) {
      bf16x8 pa0 = *(const bf16x8*)&Plds[w][lc][kp * 32 + lg * 8];
      bf16x8 pa1 = *(const bf16x8*)&Plds[w][16 + lc][kp * 32 + lg * 8];
#pragma unroll
      for (int col = 0; col < 8; ++col) {
        bf16x8 vf = *(const bf16x8*)&Vtlds[col * 16 + lc][kp * 32 + lg * 8];
        oacc[0][col] = __builtin_amdgcn_mfma_f32_16x16x32_bf16(pa0, vf, oacc[0][col], 0, 0, 0);
        oacc[1][col] = __builtin_amdgcn_mfma_f32_16x16x32_bf16(pa1, vf, oacc[1][col], 0, 0, 0);
      }
    }
  }

#pragma unroll
  for (int off = 1; off < 16; off <<= 1)
#pragma unroll
    for (int q2 = 0; q2 < 2; ++q2)
#pragma unroll
      for (int r = 0; r < 4; ++r) lsum[q2][r] += __shfl_xor(lsum[q2][r], off);

  const size_t obase = ((size_t)ks * NB + b) * NT;
#pragma unroll
  for (int q2 = 0; q2 < 2; ++q2) {
#pragma unroll
    for (int col = 0; col < 8; ++col)
#pragma unroll
      for (int r = 0; r < 4; ++r) {
        int row = q0 + q2 * 16 + lg * 4 + r;
        partO[(obase + row) * CH + col * 16 + lc] = (unsigned short)f2bf(oacc[q2][col][r]);
      }
    if (lc == 0) {
#pragma unroll
      for (int r = 0; r < 4; ++r)
        partL[obase + q0 + q2 * 16 + lg * 4 + r] = lsum[q2][r];
    }
  }
}

// ---------------------------------------------------------------- W gemm + combine (round-5 form)
__global__ __launch_bounds__(256) void k_gemmW(
    const unsigned short* __restrict__ partO, const float* __restrict__ partL,
    const unsigned short* __restrict__ wf, const float* __restrict__ bias,
    float* __restrict__ wy, unsigned short* __restrict__ wyb) {
  __shared__ __align__(16) unsigned short Al[64 * 136];
  __shared__ float linv[64];
  const int t = threadIdx.x, r0 = blockIdx.x * 64;

  if (t < 64) {
    float l = 0.f;
#pragma unroll
    for (int ks = 0; ks < ATT_KSPLIT; ++ks) l += partL[(size_t)ks * 8192 + r0 + t];
    linv[t] = 1.f / l;
  }
  __syncthreads();

#pragma unroll
  for (int i = 0; i < 4; ++i) {
    int it = t + 256 * i;
    int row = it >> 4, g = it & 15;
    float a[8] = {0.f, 0.f, 0.f, 0.f, 0.f, 0.f, 0.f, 0.f};
#pragma unroll
    for (int ks = 0; ks < ATT_KSPLIT; ++ks) {
      uint4 u = *(const uint4*)(partO + ((size_t)ks * 8192 + r0 + row) * 128 + g * 8);
      const unsigned* uw = (const unsigned*)&u;
#pragma unroll
      for (int q = 0; q < 4; ++q) {
        a[2 * q] += bf2f(uw[q] & 0xffffu);
        a[2 * q + 1] += bf2f(uw[q] >> 16);
      }
    }
    float s = linv[row];
    uint4 pk;
    pk.x = f2bf(a[0] * s) | (f2bf(a[1] * s) << 16);
    pk.y = f2bf(a[2] * s) | (f2bf(a[3] * s) << 16);
    pk.z = f2bf(a[4] * s) | (f2bf(a[5] * s) << 16);
    pk.w = f2bf(a[6] * s) | (f2bf(a[7] * s) << 16);
    *(uint4*)&Al[row * 136 + g * 8] = pk;
  }
  __syncthreads();

  const int w = t >> 6, lane = t & 63, lg = lane >> 4, lc = lane & 15;
  const int mw = w & 1, nw = w >> 1;
  f32x4 acc[2][4];
#pragma unroll
  for (int m = 0; m < 2; ++m)
#pragma unroll
    for (int n = 0; n < 4; ++n)
#pragma unroll
      for (int r = 0; r < 4; ++r) acc[m][n][r] = 0.f;
  const unsigned short* wb =
      wf + (size_t)57 * 16384 + (size_t)(nw * 4) * 2048 + lane * 8;
#pragma unroll
  for (int k = 0; k < 4; ++k) {
    bf16x8 a0 = *(const bf16x8*)&Al[(mw * 32 + lc) * 136 + k * 32 + lg * 8];
    bf16x8 a1 = *(const bf16x8*)&Al[(mw * 32 + 16 + lc) * 136 + k * 32 + lg * 8];
#pragma unroll
    for (int n = 0; n < 4; ++n) {
      bf16x8 bfr = *(const bf16x8*)(wb + n * 2048 + k * 512);
      acc[0][n] = __builtin_amdgcn_mfma_f32_16x16x32_bf16(a0, bfr, acc[0][n], 0, 0, 0);
      acc[1][n] = __builtin_amdgcn_mfma_f32_16x16x32_bf16(a1, bfr, acc[1][n], 0, 0, 0);
    }
  }
#pragma unroll
  for (int n = 0; n < 4; ++n) {
    int col = nw * 64 + n * 16 + lc;
    float bb = bias[col];
#pragma unroll
    for (int m = 0; m < 2; ++m)
#pragma unroll
      for (int r = 0; r < 4; ++r) {
        int row = r0 + mw * 32 + m * 16 + lg * 4 + r;
        float v = acc[m][n][r] + bb;
        wy[(size_t)row * 128 + col] = v;
        wyb[(size_t)row * 128 + col] = (unsigned short)f2bf(v);
      }
  }
}

// ---------------------------------------------------------------- 3x3 reflect conv (bf16 MFMA)
// 512-thread blocks, grid 256, XCD-chunked swizzle (vertical halo neighbors co-XCD).
// MODE 0: plain bf16 input. MODE 1: relu(IN(input)). MODE 2: wy_in + IN(c2) fused residual.
template <int MODE>
__global__ __launch_bounds__(512, 2) void k_conv(
    const unsigned short* __restrict__ act, const unsigned short* __restrict__ wf,
    const float* __restrict__ bias, const float* __restrict__ part_in,
    const float* __restrict__ gamma, const float* __restrict__ beta,
    unsigned short* __restrict__ outc, float* __restrict__ part_out,
    const float* __restrict__ wy_in, float* __restrict__ wy_out) {
  __shared__ unsigned short Alds[3][34 * 136];
  __shared__ float red[256];
  __shared__ float Aff[2][128];

  const int t = threadIdx.x;
  const int bx = (blockIdx.x & 7) * 32 + (blockIdx.x >> 3);  // XCD-chunked (256%8==0)
  const int xh = bx & 1, y = (bx >> 1) & 63, b = bx >> 7;
  const int w = t >> 6, lane = t & 63, lg = lane >> 4, lc = lane & 15;
  const int x0 = xh * 32;
  const int coT = w;  // 8 waves cover all 8 co-tiles

  if constexpr (MODE >= 1) {
    if (t < 256) {
      const float4* p = (const float4*)(part_in + ((size_t)b * 256 + t) * 128);
      float s0 = 0.f, s1 = 0.f, s2 = 0.f, s3 = 0.f;
#pragma unroll 8
      for (int k = 0; k < 32; ++k) {
        float4 v = p[k];
        s0 += v.x; s1 += v.y; s2 += v.z; s3 += v.w;
      }
      red[t] = (s0 + s1) + (s2 + s3);
    }
    __syncthreads();
    if (t < 128) {
      float mean = red[2 * t] * (1.f / 4096.f);
      float var = red[2 * t + 1] * (1.f / 4096.f) - mean * mean;
      float a = gamma[t] * rsqrtf(var + 1e-3f);
      Aff[0][t] = a;
      Aff[1][t] = beta[t] - mean * a;
    }
    __syncthreads();
  }

  const unsigned short* actB = act + (size_t)b * NT * CH;
#pragma unroll
  for (int i = 0; i < 4; ++i) {
    int it = t + 512 * i;
    if (it < 1632) {
      int r = it / 544, rem = it - r * 544;
      int px = rem >> 4, g = rem & 15;
      int sy = y - 1 + r;
      sy = sy < 0 ? 1 : (sy > 63 ? 62 : sy);
      int sx = x0 - 1 + px;
      sx = sx < 0 ? 1 : (sx > 63 ? 62 : sx);
      const int lpix = sy * 64 + sx;
      uint4 v = *(const uint4*)(actB + (size_t)lpix * CH + g * 8);
      if constexpr (MODE == 1) {
        int c0 = g * 8;
        unsigned* vw = (unsigned*)&v;
#pragma unroll
        for (int q = 0; q < 4; ++q) {
          float v0 = bf2f(vw[q] & 0xffffu), v1 = bf2f(vw[q] >> 16);
          v0 = fmaxf(0.f, fmaf(Aff[0][c0 + 2 * q], v0, Aff[1][c0 + 2 * q]));
          v1 = fmaxf(0.f, fmaf(Aff[0][c0 + 2 * q + 1], v1, Aff[1][c0 + 2 * q + 1]));
          vw[q] = f2bf(v0) | (f2bf(v1) << 16);
        }
      } else if constexpr (MODE == 2) {
        int c0 = g * 8;
        const size_t gpix = (size_t)b * NT + lpix;
        const float* wpin = wy_in + gpix * CH + c0;
        float4 w0 = *(const float4*)wpin, w1 = *(const float4*)(wpin + 4);
        float wv[8] = {w0.x, w0.y, w0.z, w0.w, w1.x, w1.y, w1.z, w1.w};
        const unsigned* vw = (const unsigned*)&v;
        float o[8];
#pragma unroll
        for (int q = 0; q < 8; ++q) {
          float cv = bf2f((q & 1) ? (vw[q >> 1] >> 16) : (vw[q >> 1] & 0xffffu));
          o[q] = wv[q] + fmaf(Aff[0][c0 + q], cv, Aff[1][c0 + q]);
        }
        if (r == 1 && px >= 1 && px < 33) {  // own row, interior: write residual f32
          float* wpo = wy_out + gpix * CH + c0;
          *(float4*)wpo = make_float4(o[0], o[1], o[2], o[3]);
          *(float4*)(wpo + 4) = make_float4(o[4], o[5], o[6], o[7]);
        }
        uint4 pk;
        pk.x = f2bf(o[0]) | (f2bf(o[1]) << 16);
        pk.y = f2bf(o[2]) | (f2bf(o[3]) << 16);
        pk.z = f2bf(o[4]) | (f2bf(o[5]) << 16);
        pk.w = f2bf(o[6]) | (f2bf(o[7]) << 16);
        v = pk;
      }
      *(uint4*)&Alds[r][px * 136 + g * 8] = v;
    }
  }
  __syncthreads();

  f32x4 acc[2];
#pragma unroll
  for (int m = 0; m < 2; ++m)
#pragma unroll
    for (int r = 0; r < 4; ++r) acc[m][r] = 0.f;

  const unsigned short* wbase = wf + (size_t)coT * 2048 + lane * 8;
  bf16x8 wc[4], wn[4];
#pragma unroll
  for (int k = 0; k < 4; ++k) wc[k] = *(const bf16x8*)(wbase + k * 512);
#pragma unroll
  for (int tap = 0; tap < 9; ++tap) {
    const int dy = tap / 3, dx = tap - dy * 3;
    if (tap < 8) {
#pragma unroll
      for (int k = 0; k < 4; ++k)
        wn[k] = *(const bf16x8*)(wbase + (size_t)(tap + 1) * 16384 + k * 512);
    }
#pragma unroll
    for (int k = 0; k < 4; ++k) {
      bf16x8 a0 = *(const bf16x8*)&Alds[dy][(dx + lc) * 136 + k * 32 + lg * 8];
      bf16x8 a1 = *(const bf16x8*)&Alds[dy][(dx + 16 + lc) * 136 + k * 32 + lg * 8];
      acc[0] = __builtin_amdgcn_mfma_f32_16x16x32_bf16(a0, wc[k], acc[0], 0, 0, 0);
      acc[1] = __builtin_amdgcn_mfma_f32_16x16x32_bf16(a1, wc[k], acc[1], 0, 0, 0);
    }
#pragma unroll
    for (int k = 0; k < 4; ++k) wc[k] = wn[k];
  }

  const int col = coT * 16 + lc;
  const float bs = bias[col];
  float sum = 0.f, sq = 0.f;
  unsigned short* outB = outc + (size_t)(b * NT + y * 64 + x0) * CH;
#pragma unroll
  for (int m = 0; m < 2; ++m)
#pragma unroll
    for (int r = 0; r < 4; ++r) {
      float v = acc[m][r] + bs;
      int px = m * 16 + lg * 4 + r;
      outB[(size_t)px * CH + col] = (unsigned short)f2bf(v);
      sum += v;
      sq = fmaf(v, v, sq);
    }
  sum += __shfl_xor(sum, 16);
  sum += __shfl_xor(sum, 32);
  sq += __shfl_xor(sq, 16);
  sq += __shfl_xor(sq, 32);
  if (lg == 0) {
    const int pg = y * 2 + xh;
    part_out[((size_t)(b * 128 + col) * 2 + 0) * 128 + pg] = sum;
    part_out[((size_t)(b * 128 + col) * 2 + 1) * 128 + pg] = sq;
  }
}

// ---------------------------------------------------------------- final residual (+stats reduce, +blend)
__global__ __launch_bounds__(256) void k_residual_final(
    const unsigned short* __restrict__ c2v, const float* __restrict__ part_in,
    const float* __restrict__ gamma, const float* __restrict__ beta,
    const float* __restrict__ wy, const float* __restrict__ x,
    const float* __restrict__ mask, float* __restrict__ out) {
  __shared__ float red[256];
  __shared__ float AffA[128];
  __shared__ float AffB[128];
  const int t = threadIdx.x, bx = blockIdx.x;
  const int b = bx >> 8;

  {
    const float4* p = (const float4*)(part_in + ((size_t)b * 256 + t) * 128);
    float s0 = 0.f, s1 = 0.f, s2 = 0.f, s3 = 0.f;
#pragma unroll 8
    for (int k = 0; k < 32; ++k) {
      float4 v = p[k];
      s0 += v.x; s1 += v.y; s2 += v.z; s3 += v.w;
    }
    red[t] = (s0 + s1) + (s2 + s3);
  }
  __syncthreads();
  if (t < 128) {
    float mean = red[2 * t] * (1.f / 4096.f);
    float var = red[2 * t + 1] * (1.f / 4096.f) - mean * mean;
    float a = gamma[t] * rsqrtf(var + 1e-3f);
    AffA[t] = a;
    AffB[t] = beta[t] - mean * a;
  }
  __syncthreads();

  const int idx = bx * 256 + t;
  const int g = idx & 15;
  const int pixel = idx >> 4;
  const int c0 = g * 8;
  uint4 v = *(const uint4*)(c2v + (size_t)pixel * CH + c0);
  const float* wp_ = wy + (size_t)pixel * CH + c0;
  float4 w0 = *(const float4*)wp_, w1 = *(const float4*)(wp_ + 4);
  float wv[8] = {w0.x, w0.y, w0.z, w0.w, w1.x, w1.y, w1.z, w1.w};
  const unsigned* vw = (const unsigned*)&v;
  float o[8];
#pragma unroll
  for (int q = 0; q < 8; ++q) {
    float cv = bf2f((q & 1) ? (vw[q >> 1] >> 16) : (vw[q >> 1] & 0xffffu));
    o[q] = wv[q] + fmaf(AffA[c0 + q], cv, AffB[c0 + q]);
  }
  const float m = maskval(mask[pixel]);
  const float* xp = x + (size_t)pixel * CH + c0;
  float4 x0 = *(const float4*)xp, x1 = *(const float4*)(xp + 4);
  float xv[8] = {x0.x, x0.y, x0.z, x0.w, x1.x, x1.y, x1.z, x1.w};
  float* op = out + (size_t)pixel * CH + c0;
  float r[8];
#pragma unroll
  for (int q = 0; q < 8; ++q) r[q] = m * xv[q] + (1.f - m) * o[q];
  *(float4*)op = make_float4(r[0], r[1], r[2], r[3]);
  *(float4*)(op + 4) = make_float4(r[4], r[5], r[6], r[7]);
}

// ================================================================ launch
extern "C" void kernel_launch(void* const* d_in, const int* in_sizes, int n_in,
                              void* d_out, int out_size, void* d_ws, size_t ws_size,
                              hipStream_t stream) {
  (void)in_sizes; (void)n_in; (void)out_size; (void)ws_size;
  const float* x    = (const float*)d_in[0];
  const float* mask = (const float*)d_in[1];
  const float* wg   = (const float*)d_in[2];
  const float* bg   = (const float*)d_in[3];
  const float* wt   = (const float*)d_in[4];
  const float* bt   = (const float*)d_in[5];
  const float* wp   = (const float*)d_in[6];
  const float* bp   = (const float*)d_in[7];
  const float* ww   = (const float*)d_in[8];
  const float* bw   = (const float*)d_in[9];
  const float* rw1  = (const float*)d_in[10];
  const float* rb1  = (const float*)d_in[11];
  const float* rg1  = (const float*)d_in[12];
  const float* rbe1 = (const float*)d_in[13];
  const float* rw2  = (const float*)d_in[14];
  const float* rb2  = (const float*)d_in[15];
  const float* rg2  = (const float*)d_in[16];
  const float* rbe2 = (const float*)d_in[17];
  float* out = (float*)d_out;

  char* W = (char*)d_ws;
  unsigned short* wfrag = (unsigned short*)W;                     // 58*32 KB = 1.81 MB
  char* base = W + 2097152;
  unsigned short* thb   = (unsigned short*)(base);                // 2 MB
  unsigned short* phb   = (unsigned short*)(base + 2097152);      // 2 MB
  unsigned short* vtb   = (unsigned short*)(base + 2 * 2097152);  // 2 MB
  float*          partL = (float*)(base + 3 * 2097152);           // 256 KB
  unsigned short* partO = (unsigned short*)(base + 3 * 2097152 + 262144);  // 16 MB
  // aliases over dead regions
  float*          wy0   = (float*)(base);                          // 4 MB over thb+phb
  unsigned short* wyb   = (unsigned short*)(base + 2 * 2097152);   // 2 MB over vtb
  unsigned short* c1    = partO;                                   // 2 MB
  unsigned short* c2    = (unsigned short*)((char*)partO + 2097152);       // 2 MB
  float*          partA = (float*)((char*)partO + 2 * 2097152);    // 256 KB
  float*          partB = (float*)((char*)partO + 2 * 2097152 + 262144);   // 256 KB
  float*          wy1   = (float*)((char*)partO + 5 * 1048576);    // 4 MB

  k_prepw<<<232, 256, 0, stream>>>(rw1, rw2, wt, wp, wg, ww, wfrag);
  k_proj3<<<128, 256, 0, stream>>>(x, mask, wfrag, bt, bp, bg, thb, phb, vtb);
  k_attn<<<512, 256, 0, stream>>>(thb, phb, vtb, partO, partL);
  k_gemmW<<<128, 256, 0, stream>>>(partO, partL, wfrag, bw, wy0, wyb);

  const unsigned short* wf1_0 = wfrag;
  const unsigned short* wf2_0 = wfrag + (size_t)1 * 9 * 16384;
  const unsigned short* wf1_1 = wfrag + (size_t)2 * 9 * 16384;
  const unsigned short* wf2_1 = wfrag + (size_t)3 * 9 * 16384;
  const unsigned short* wf1_2 = wfrag + (size_t)4 * 9 * 16384;
  const unsigned short* wf2_2 = wfrag + (size_t)5 * 9 * 16384;

  // block 0
  k_conv<0><<<256, 512, 0, stream>>>(wyb, wf1_0, rb1, nullptr, nullptr, nullptr,
                                     c1, partA, nullptr, nullptr);
  k_conv<1><<<256, 512, 0, stream>>>(c1, wf2_0, rb2, partA, rg1, rbe1,
                                     c2, partB, nullptr, nullptr);
  // block 1 (conv1 fuses residual(0): wy0 -> wy1)
  k_conv<2><<<256, 512, 0, stream>>>(c2, wf1_1, rb1 + 128, partB, rg2, rbe2,
                                     c1, partA, wy0, wy1);
  k_conv<1><<<256, 512, 0, stream>>>(c1, wf2_1, rb2 + 128, partA, rg1 + 128,
                                     rbe1 + 128, c2, partB, nullptr, nullptr);
  // block 2 (conv1 fuses residual(1): wy1 -> wy0)
  k_conv<2><<<256, 512, 0, stream>>>(c2, wf1_2, rb1 + 256, partB, rg2 + 128,
                                     rbe2 + 128, c1, partA, wy1, wy0);
  k_conv<1><<<256, 512, 0, stream>>>(c1, wf2_2, rb2 + 256, partA, rg1 + 256,
                                     rbe1 + 256, c2, partB, nullptr, nullptr);
  // final residual(2) + blend
  k_residual_final<<<512, 256, 0, stream>>>(c2, partB, rg2 + 256, rbe2 + 256,
                                            wy0, x, mask, out);
}

// Round 16
// 127.582 us; speedup vs baseline: 1.2236x; 1.0444x over previous
//
#include <hip/hip_runtime.h>
#include <math.h>

constexpr int NB = 2;           // batch
constexpr int IMG = 64;         // H == W
constexpr int CH = 128;         // channels
constexpr int NT = IMG * IMG;   // 4096 tokens per batch
constexpr int ATT_KSPLIT = 8;
constexpr int KPS = NT / ATT_KSPLIT;  // 512 keys per split

typedef __bf16 bf16x8 __attribute__((ext_vector_type(8)));
typedef float f32x4 __attribute__((ext_vector_type(4)));

__device__ __forceinline__ unsigned f2bf(float x) {  // RNE float->bf16 bits
  unsigned u = __float_as_uint(x);
  return (u + 0x7fffu + ((u >> 16) & 1u)) >> 16;
}
__device__ __forceinline__ float bf2f(unsigned h) {
  return __uint_as_float(h << 16);
}
__device__ __forceinline__ float maskval(float mk) {
  float mm = mk > 0.f ? 0.f : mk;
  return (1.f - mm) * (1.f - mk);
}

// ---------------------------------------------------------------- weight prep (sliced, 232 blocks)
__global__ __launch_bounds__(256) void k_prepw(
    const float* __restrict__ rw1, const float* __restrict__ rw2,
    const float* __restrict__ wt_, const float* __restrict__ wp_,
    const float* __restrict__ wg_, const float* __restrict__ ww_,
    unsigned short* __restrict__ wfrag) {
  __shared__ float Ws[32][132];
  const int t = threadIdx.x;
  const int tile = blockIdx.x >> 2, slice = blockIdx.x & 3;
  const float* src;
  if (tile < 54) {
    int i2 = tile / 9, tap = tile - i2 * 9;
    int blk = i2 >> 1;
    src = ((i2 & 1) ? rw2 : rw1) + ((size_t)blk * 9 + tap) * 16384;
  } else {
    src = tile == 54 ? wt_ : tile == 55 ? wp_ : tile == 56 ? wg_ : ww_;
  }
#pragma unroll
  for (int k = 0; k < 4; ++k) {
    int i4 = t + 256 * k;
    int row = i4 >> 5, c4 = (i4 & 31) << 2;
    *(float4*)&Ws[row][c4] =
        *(const float4*)(src + (size_t)(slice * 32 + row) * 128 + c4);
  }
  __syncthreads();
  unsigned short* dst = wfrag + (size_t)tile * 16384;
#pragma unroll
  for (int i = 0; i < 2; ++i) {
    int it = t + 256 * i;  // 0..511: cotile*64 + lane
    int cotile = it >> 6, lane = it & 63;
    int lg = lane >> 4, lc = lane & 15;
    int co = cotile * 16 + lc, r0 = lg * 8;  // local ci row
    unsigned u0 = f2bf(Ws[r0 + 0][co]) | (f2bf(Ws[r0 + 1][co]) << 16);
    unsigned u1 = f2bf(Ws[r0 + 2][co]) | (f2bf(Ws[r0 + 3][co]) << 16);
    unsigned u2 = f2bf(Ws[r0 + 4][co]) | (f2bf(Ws[r0 + 5][co]) << 16);
    unsigned u3 = f2bf(Ws[r0 + 6][co]) | (f2bf(Ws[r0 + 7][co]) << 16);
    int idx = cotile * 256 + slice * 64 + lane;
    *(uint4*)(dst + (size_t)idx * 8) = make_uint4(u0, u1, u2, u3);
  }
}

// ---------------------------------------------------------------- fused projections
// 32 rows/block (grid 256, all CUs). Validated on-device in round 6.
__global__ __launch_bounds__(256) void k_proj3(
    const float* __restrict__ x, const float* __restrict__ mask,
    const unsigned short* __restrict__ wf, const float* __restrict__ bt_,
    const float* __restrict__ bp_, const float* __restrict__ bg_,
    unsigned short* __restrict__ thb, unsigned short* __restrict__ phb,
    unsigned short* __restrict__ vtb) {
  __shared__ __align__(16) unsigned short Al[32 * 136];
  __shared__ __align__(16) unsigned short Tl[32 * 136];
  const int t = threadIdx.x, r0 = blockIdx.x * 32, b = r0 >> 12;

#pragma unroll
  for (int k = 0; k < 2; ++k) {
    int it = t + 256 * k;
    int row = it >> 4, g = it & 15;
    const float* s = x + (size_t)(r0 + row) * 128 + g * 8;
    float4 v0 = *(const float4*)s, v1 = *(const float4*)(s + 4);
    uint4 pk;
    pk.x = f2bf(v0.x) | (f2bf(v0.y) << 16);
    pk.y = f2bf(v0.z) | (f2bf(v0.w) << 16);
    pk.z = f2bf(v1.x) | (f2bf(v1.y) << 16);
    pk.w = f2bf(v1.z) | (f2bf(v1.w) << 16);
    *(uint4*)&Al[row * 136 + g * 8] = pk;
  }
  __syncthreads();

  const int w = t >> 6, lane = t & 63, lg = lane >> 4, lc = lane & 15;
  const int mw = w & 1, nw = w >> 1;
#pragma unroll
  for (int mat = 0; mat < 3; ++mat) {
    // all 16 weight fragments upfront -> regs
    const unsigned short* wb =
        wf + (size_t)(54 + mat) * 16384 + (size_t)(nw * 4) * 2048 + lane * 8;
    bf16x8 wr[4][4];
#pragma unroll
    for (int n = 0; n < 4; ++n)
#pragma unroll
      for (int k = 0; k < 4; ++k)
        wr[n][k] = *(const bf16x8*)(wb + n * 2048 + k * 512);

    f32x4 acc[4];
#pragma unroll
    for (int n = 0; n < 4; ++n)
#pragma unroll
      for (int r = 0; r < 4; ++r) acc[n][r] = 0.f;
#pragma unroll
    for (int k = 0; k < 4; ++k) {
      bf16x8 a0 = *(const bf16x8*)&Al[(mw * 16 + lc) * 136 + k * 32 + lg * 8];
#pragma unroll
      for (int n = 0; n < 4; ++n)
        acc[n] = __builtin_amdgcn_mfma_f32_16x16x32_bf16(a0, wr[n][k], acc[n], 0, 0, 0);
    }
    const float* bs = mat == 0 ? bt_ : mat == 1 ? bp_ : bg_;
    float bbv[4];
#pragma unroll
    for (int n = 0; n < 4; ++n) bbv[n] = bs[nw * 64 + n * 16 + lc];

    if (mat < 2) {
      unsigned short* ob = mat == 0 ? thb : phb;
#pragma unroll
      for (int n = 0; n < 4; ++n) {
        int col = nw * 64 + n * 16 + lc;
#pragma unroll
        for (int r = 0; r < 4; ++r) {
          int row = r0 + mw * 16 + lg * 4 + r;
          ob[(size_t)row * 128 + col] = (unsigned short)f2bf(acc[n][r] + bbv[n]);
        }
      }
    } else {
#pragma unroll
      for (int r = 0; r < 4; ++r) {
        int rl = mw * 16 + lg * 4 + r;
        float mvv = maskval(mask[r0 + rl]);
#pragma unroll
        for (int n = 0; n < 4; ++n) {
          int col = nw * 64 + n * 16 + lc;
          Tl[rl * 136 + col] = (unsigned short)f2bf((acc[n][r] + bbv[n]) * mvv);
        }
      }
      __syncthreads();
      const int c = t >> 1, h = t & 1;
      unsigned buf[8];
#pragma unroll
      for (int j = 0; j < 8; ++j)
        buf[j] = (unsigned)Tl[(h * 16 + 2 * j) * 136 + c] |
                 ((unsigned)Tl[(h * 16 + 2 * j + 1) * 136 + c] << 16);
      const int key0 = r0 & (NT - 1);
      unsigned short* dst = vtb + ((size_t)b * CH + c) * NT + key0 + h * 16;
      *(uint4*)dst = make_uint4(buf[0], buf[1], buf[2], buf[3]);
      *(uint4*)(dst + 8) = make_uint4(buf[4], buf[5], buf[6], buf[7]);
    }
  }
}

// ---------------------------------------------------------------- flash attention (round-15 exact:
// qt-fastest decomposition + XCD-chunked block swizzle)
__global__ __launch_bounds__(256, 2) void k_attn(
    const unsigned short* __restrict__ theta, const unsigned short* __restrict__ phi,
    const unsigned short* __restrict__ vt, unsigned short* __restrict__ partO,
    float* __restrict__ partL) {
  __shared__ __align__(16) unsigned short Klds[64][136];
  __shared__ __align__(16) unsigned short Vtlds[128][72];
  __shared__ __align__(16) unsigned short Plds[4][32][72];

  const int t = threadIdx.x;
  const int bx = (blockIdx.x & 7) * 64 + (blockIdx.x >> 3);  // XCD-chunked (512%8==0)
  const int qt = bx & 31;
  const int ks = (bx >> 5) & 7;
  const int b = bx >> 8;
  const int w = t >> 6;
  const int lane = t & 63;
  const int lg = lane >> 4;
  const int lc = lane & 15;
  const int q0 = qt * 128 + w * 32;

  const unsigned short* thB = theta + (size_t)b * NT * CH;
  const unsigned short* phB = phi + (size_t)b * NT * CH;
  const unsigned short* vtB = vt + (size_t)b * CH * NT;

  bf16x8 qf[2][4];
#pragma unroll
  for (int q2 = 0; q2 < 2; ++q2)
#pragma unroll
    for (int k = 0; k < 4; ++k)
      qf[q2][k] = *(const bf16x8*)(thB + (size_t)(q0 + q2 * 16 + lc) * CH + k * 32 + lg * 8);

  f32x4 oacc[2][8];
#pragma unroll
  for (int q2 = 0; q2 < 2; ++q2)
#pragma unroll
    for (int c = 0; c < 8; ++c)
#pragma unroll
      for (int r = 0; r < 4; ++r) oacc[q2][c][r] = 0.f;
  float lsum[2][4] = {{0.f, 0.f, 0.f, 0.f}, {0.f, 0.f, 0.f, 0.f}};

  for (int kt = 0; kt < KPS; kt += 64) {
    const int key0 = ks * KPS + kt;
    __syncthreads();
#pragma unroll
    for (int i = 0; i < 4; ++i) {
      int idx = t + 256 * i;
      int row = idx >> 4, c8 = (idx & 15) * 8;
      *(uint4*)&Klds[row][c8] = *(const uint4*)(phB + (size_t)(key0 + row) * CH + c8);
      int rowv = idx >> 3, k8 = (idx & 7) * 8;
      *(uint4*)&Vtlds[rowv][k8] = *(const uint4*)(vtB + (size_t)rowv * NT + key0 + k8);
    }
    __syncthreads();

#pragma unroll
    for (int col = 0; col < 4; ++col) {
      bf16x8 kf[4];
#pragma unroll
      for (int k = 0; k < 4; ++k)
        kf[k] = *(const bf16x8*)&Klds[col * 16 + lc][k * 32 + lg * 8];
      f32x4 s0, s1;
#pragma unroll
      for (int r = 0; r < 4; ++r) { s0[r] = 0.f; s1[r] = 0.f; }
#pragma unroll
      for (int k = 0; k < 4; ++k) {
        s0 = __builtin_amdgcn_mfma_f32_16x16x32_bf16(qf[0][k], kf[k], s0, 0, 0, 0);
        s1 = __builtin_amdgcn_mfma_f32_16x16x32_bf16(qf[1][k], kf[k], s1, 0, 0, 0);
      }
#pragma unroll
      for (int r = 0; r < 4; ++r) {
        float p0 = __expf(s0[r]);
        lsum[0][r] += p0;
        Plds[w][lg * 4 + r][col * 16 + lc] = (unsigned short)f2bf(p0);
        float p1 = __expf(s1[r]);
        lsum[1][r] += p1;
        Plds[w][16 + lg * 4 + r][col * 16 + lc] = (unsigned short)f2bf(p1);
      }
    }

#pragma unroll
    for (int kp = 0; kp < 2; ++kp) {
      bf16x8 pa0 = *(const bf16x8*)&Plds[w][lc][kp * 32 + lg * 8];
      bf16x8 pa1 = *(const bf16x8*)&Plds[w][16 + lc][kp * 32 + lg * 8];
#pragma unroll
      for (int col = 0; col < 8; ++col) {
        bf16x8 vf = *(const bf16x8*)&Vtlds[col * 16 + lc][kp * 32 + lg * 8];
        oacc[0][col] = __builtin_amdgcn_mfma_f32_16x16x32_bf16(pa0, vf, oacc[0][col], 0, 0, 0);
        oacc[1][col] = __builtin_amdgcn_mfma_f32_16x16x32_bf16(pa1, vf, oacc[1][col], 0, 0, 0);
      }
    }
  }

#pragma unroll
  for (int off = 1; off < 16; off <<= 1)
#pragma unroll
    for (int q2 = 0; q2 < 2; ++q2)
#pragma unroll
      for (int r = 0; r < 4; ++r) lsum[q2][r] += __shfl_xor(lsum[q2][r], off);

  const size_t obase = ((size_t)ks * NB + b) * NT;
#pragma unroll
  for (int q2 = 0; q2 < 2; ++q2) {
#pragma unroll
    for (int col = 0; col < 8; ++col)
#pragma unroll
      for (int r = 0; r < 4; ++r) {
        int row = q0 + q2 * 16 + lg * 4 + r;
        partO[(obase + row) * CH + col * 16 + lc] = (unsigned short)f2bf(oacc[q2][col][r]);
      }
    if (lc == 0) {
#pragma unroll
      for (int r = 0; r < 4; ++r)
        partL[obase + q0 + q2 * 16 + lg * 4 + r] = lsum[q2][r];
    }
  }
}

// ---------------------------------------------------------------- W gemm + combine
// 32 rows/block (grid 256, all CUs). Validated on-device in round 6.
__global__ __launch_bounds__(256) void k_gemmW(
    const unsigned short* __restrict__ partO, const float* __restrict__ partL,
    const unsigned short* __restrict__ wf, const float* __restrict__ bias,
    float* __restrict__ wy, unsigned short* __restrict__ wyb) {
  __shared__ __align__(16) unsigned short Al[32 * 136];
  __shared__ float linv[32];
  const int t = threadIdx.x, r0 = blockIdx.x * 32;

  if (t < 32) {
    float l = 0.f;
#pragma unroll
    for (int ks = 0; ks < ATT_KSPLIT; ++ks) l += partL[(size_t)ks * 8192 + r0 + t];
    linv[t] = 1.f / l;
  }
  __syncthreads();

#pragma unroll
  for (int i = 0; i < 2; ++i) {
    int it = t + 256 * i;
    int row = it >> 4, g = it & 15;
    float a[8] = {0.f, 0.f, 0.f, 0.f, 0.f, 0.f, 0.f, 0.f};
#pragma unroll
    for (int ks = 0; ks < ATT_KSPLIT; ++ks) {
      uint4 u = *(const uint4*)(partO + ((size_t)ks * 8192 + r0 + row) * 128 + g * 8);
      const unsigned* uw = (const unsigned*)&u;
#pragma unroll
      for (int q = 0; q < 4; ++q) {
        a[2 * q] += bf2f(uw[q] & 0xffffu);
        a[2 * q + 1] += bf2f(uw[q] >> 16);
      }
    }
    float s = linv[row];
    uint4 pk;
    pk.x = f2bf(a[0] * s) | (f2bf(a[1] * s) << 16);
    pk.y = f2bf(a[2] * s) | (f2bf(a[3] * s) << 16);
    pk.z = f2bf(a[4] * s) | (f2bf(a[5] * s) << 16);
    pk.w = f2bf(a[6] * s) | (f2bf(a[7] * s) << 16);
    *(uint4*)&Al[row * 136 + g * 8] = pk;
  }
  __syncthreads();

  const int w = t >> 6, lane = t & 63, lg = lane >> 4, lc = lane & 15;
  const int mw = w & 1, nw = w >> 1;
  const unsigned short* wb =
      wf + (size_t)57 * 16384 + (size_t)(nw * 4) * 2048 + lane * 8;
  bf16x8 wr[4][4];
#pragma unroll
  for (int n = 0; n < 4; ++n)
#pragma unroll
    for (int k = 0; k < 4; ++k)
      wr[n][k] = *(const bf16x8*)(wb + n * 2048 + k * 512);

  f32x4 acc[4];
#pragma unroll
  for (int n = 0; n < 4; ++n)
#pragma unroll
    for (int r = 0; r < 4; ++r) acc[n][r] = 0.f;
#pragma unroll
  for (int k = 0; k < 4; ++k) {
    bf16x8 a0 = *(const bf16x8*)&Al[(mw * 16 + lc) * 136 + k * 32 + lg * 8];
#pragma unroll
    for (int n = 0; n < 4; ++n)
      acc[n] = __builtin_amdgcn_mfma_f32_16x16x32_bf16(a0, wr[n][k], acc[n], 0, 0, 0);
  }
#pragma unroll
  for (int n = 0; n < 4; ++n) {
    int col = nw * 64 + n * 16 + lc;
    float bb = bias[col];
#pragma unroll
    for (int r = 0; r < 4; ++r) {
      int row = r0 + mw * 16 + lg * 4 + r;
      float v = acc[n][r] + bb;
      wy[(size_t)row * 128 + col] = v;
      wyb[(size_t)row * 128 + col] = (unsigned short)f2bf(v);
    }
  }
}

// ---------------------------------------------------------------- 3x3 reflect conv (round-15 exact)
template <int MODE>
__global__ __launch_bounds__(512, 2) void k_conv(
    const unsigned short* __restrict__ act, const unsigned short* __restrict__ wf,
    const float* __restrict__ bias, const float* __restrict__ part_in,
    const float* __restrict__ gamma, const float* __restrict__ beta,
    unsigned short* __restrict__ outc, float* __restrict__ part_out,
    const float* __restrict__ wy_in, float* __restrict__ wy_out) {
  __shared__ unsigned short Alds[3][34 * 136];
  __shared__ float red[256];
  __shared__ float Aff[2][128];

  const int t = threadIdx.x;
  const int bx = (blockIdx.x & 7) * 32 + (blockIdx.x >> 3);  // XCD-chunked (256%8==0)
  const int xh = bx & 1, y = (bx >> 1) & 63, b = bx >> 7;
  const int w = t >> 6, lane = t & 63, lg = lane >> 4, lc = lane & 15;
  const int x0 = xh * 32;
  const int coT = w;  // 8 waves cover all 8 co-tiles

  if constexpr (MODE >= 1) {
    if (t < 256) {
      const float4* p = (const float4*)(part_in + ((size_t)b * 256 + t) * 128);
      float s0 = 0.f, s1 = 0.f, s2 = 0.f, s3 = 0.f;
#pragma unroll 8
      for (int k = 0; k < 32; ++k) {
        float4 v = p[k];
        s0 += v.x; s1 += v.y; s2 += v.z; s3 += v.w;
      }
      red[t] = (s0 + s1) + (s2 + s3);
    }
    __syncthreads();
    if (t < 128) {
      float mean = red[2 * t] * (1.f / 4096.f);
      float var = red[2 * t + 1] * (1.f / 4096.f) - mean * mean;
      float a = gamma[t] * rsqrtf(var + 1e-3f);
      Aff[0][t] = a;
      Aff[1][t] = beta[t] - mean * a;
    }
    __syncthreads();
  }

  const unsigned short* actB = act + (size_t)b * NT * CH;
#pragma unroll
  for (int i = 0; i < 4; ++i) {
    int it = t + 512 * i;
    if (it < 1632) {
      int r = it / 544, rem = it - r * 544;
      int px = rem >> 4, g = rem & 15;
      int sy = y - 1 + r;
      sy = sy < 0 ? 1 : (sy > 63 ? 62 : sy);
      int sx = x0 - 1 + px;
      sx = sx < 0 ? 1 : (sx > 63 ? 62 : sx);
      const int lpix = sy * 64 + sx;
      uint4 v = *(const uint4*)(actB + (size_t)lpix * CH + g * 8);
      if constexpr (MODE == 1) {
        int c0 = g * 8;
        unsigned* vw = (unsigned*)&v;
#pragma unroll
        for (int q = 0; q < 4; ++q) {
          float v0 = bf2f(vw[q] & 0xffffu), v1 = bf2f(vw[q] >> 16);
          v0 = fmaxf(0.f, fmaf(Aff[0][c0 + 2 * q], v0, Aff[1][c0 + 2 * q]));
          v1 = fmaxf(0.f, fmaf(Aff[0][c0 + 2 * q + 1], v1, Aff[1][c0 + 2 * q + 1]));
          vw[q] = f2bf(v0) | (f2bf(v1) << 16);
        }
      } else if constexpr (MODE == 2) {
        int c0 = g * 8;
        const size_t gpix = (size_t)b * NT + lpix;
        const float* wpin = wy_in + gpix * CH + c0;
        float4 w0 = *(const float4*)wpin, w1 = *(const float4*)(wpin + 4);
        float wv[8] = {w0.x, w0.y, w0.z, w0.w, w1.x, w1.y, w1.z, w1.w};
        const unsigned* vw = (const unsigned*)&v;
        float o[8];
#pragma unroll
        for (int q = 0; q < 8; ++q) {
          float cv = bf2f((q & 1) ? (vw[q >> 1] >> 16) : (vw[q >> 1] & 0xffffu));
          o[q] = wv[q] + fmaf(Aff[0][c0 + q], cv, Aff[1][c0 + q]);
        }
        if (r == 1 && px >= 1 && px < 33) {  // own row, interior: write residual f32
          float* wpo = wy_out + gpix * CH + c0;
          *(float4*)wpo = make_float4(o[0], o[1], o[2], o[3]);
          *(float4*)(wpo + 4) = make_float4(o[4], o[5], o[6], o[7]);
        }
        uint4 pk;
        pk.x = f2bf(o[0]) | (f2bf(o[1]) << 16);
        pk.y = f2bf(o[2]) | (f2bf(o[3]) << 16);
        pk.z = f2bf(o[4]) | (f2bf(o[5]) << 16);
        pk.w = f2bf(o[6]) | (f2bf(o[7]) << 16);
        v = pk;
      }
      *(uint4*)&Alds[r][px * 136 + g * 8] = v;
    }
  }
  __syncthreads();

  f32x4 acc[2];
#pragma unroll
  for (int m = 0; m < 2; ++m)
#pragma unroll
    for (int r = 0; r < 4; ++r) acc[m][r] = 0.f;

  const unsigned short* wbase = wf + (size_t)coT * 2048 + lane * 8;
  bf16x8 wc[4], wn[4];
#pragma unroll
  for (int k = 0; k < 4; ++k) wc[k] = *(const bf16x8*)(wbase + k * 512);
#pragma unroll
  for (int tap = 0; tap < 9; ++tap) {
    const int dy = tap / 3, dx = tap - dy * 3;
    if (tap < 8) {
#pragma unroll
      for (int k = 0; k < 4; ++k)
        wn[k] = *(const bf16x8*)(wbase + (size_t)(tap + 1) * 16384 + k * 512);
    }
#pragma unroll
    for (int k = 0; k < 4; ++k) {
      bf16x8 a0 = *(const bf16x8*)&Alds[dy][(dx + lc) * 136 + k * 32 + lg * 8];
      bf16x8 a1 = *(const bf16x8*)&Alds[dy][(dx + 16 + lc) * 136 + k * 32 + lg * 8];
      acc[0] = __builtin_amdgcn_mfma_f32_16x16x32_bf16(a0, wc[k], acc[0], 0, 0, 0);
      acc[1] = __builtin_amdgcn_mfma_f32_16x16x32_bf16(a1, wc[k], acc[1], 0, 0, 0);
    }
#pragma unroll
    for (int k = 0; k < 4; ++k) wc[k] = wn[k];
  }

  const int col = coT * 16 + lc;
  const float bs = bias[col];
  float sum = 0.f, sq = 0.f;
  unsigned short* outB = outc + (size_t)(b * NT + y * 64 + x0) * CH;
#pragma unroll
  for (int m = 0; m < 2; ++m)
#pragma unroll
    for (int r = 0; r < 4; ++r) {
      float v = acc[m][r] + bs;
      int px = m * 16 + lg * 4 + r;
      outB[(size_t)px * CH + col] = (unsigned short)f2bf(v);
      sum += v;
      sq = fmaf(v, v, sq);
    }
  sum += __shfl_xor(sum, 16);
  sum += __shfl_xor(sum, 32);
  sq += __shfl_xor(sq, 16);
  sq += __shfl_xor(sq, 32);
  if (lg == 0) {
    const int pg = y * 2 + xh;
    part_out[((size_t)(b * 128 + col) * 2 + 0) * 128 + pg] = sum;
    part_out[((size_t)(b * 128 + col) * 2 + 1) * 128 + pg] = sq;
  }
}

// ---------------------------------------------------------------- final residual (+stats reduce, +blend)
__global__ __launch_bounds__(256) void k_residual_final(
    const unsigned short* __restrict__ c2v, const float* __restrict__ part_in,
    const float* __restrict__ gamma, const float* __restrict__ beta,
    const float* __restrict__ wy, const float* __restrict__ x,
    const float* __restrict__ mask, float* __restrict__ out) {
  __shared__ float red[256];
  __shared__ float AffA[128];
  __shared__ float AffB[128];
  const int t = threadIdx.x, bx = blockIdx.x;
  const int b = bx >> 8;

  {
    const float4* p = (const float4*)(part_in + ((size_t)b * 256 + t) * 128);
    float s0 = 0.f, s1 = 0.f, s2 = 0.f, s3 = 0.f;
#pragma unroll 8
    for (int k = 0; k < 32; ++k) {
      float4 v = p[k];
      s0 += v.x; s1 += v.y; s2 += v.z; s3 += v.w;
    }
    red[t] = (s0 + s1) + (s2 + s3);
  }
  __syncthreads();
  if (t < 128) {
    float mean = red[2 * t] * (1.f / 4096.f);
    float var = red[2 * t + 1] * (1.f / 4096.f) - mean * mean;
    float a = gamma[t] * rsqrtf(var + 1e-3f);
    AffA[t] = a;
    AffB[t] = beta[t] - mean * a;
  }
  __syncthreads();

  const int idx = bx * 256 + t;
  const int g = idx & 15;
  const int pixel = idx >> 4;
  const int c0 = g * 8;
  uint4 v = *(const uint4*)(c2v + (size_t)pixel * CH + c0);
  const float* wp_ = wy + (size_t)pixel * CH + c0;
  float4 w0 = *(const float4*)wp_, w1 = *(const float4*)(wp_ + 4);
  float wv[8] = {w0.x, w0.y, w0.z, w0.w, w1.x, w1.y, w1.z, w1.w};
  const unsigned* vw = (const unsigned*)&v;
  float o[8];
#pragma unroll
  for (int q = 0; q < 8; ++q) {
    float cv = bf2f((q & 1) ? (vw[q >> 1] >> 16) : (vw[q >> 1] & 0xffffu));
    o[q] = wv[q] + fmaf(AffA[c0 + q], cv, AffB[c0 + q]);
  }
  const float m = maskval(mask[pixel]);
  const float* xp = x + (size_t)pixel * CH + c0;
  float4 x0 = *(const float4*)xp, x1 = *(const float4*)(xp + 4);
  float xv[8] = {x0.x, x0.y, x0.z, x0.w, x1.x, x1.y, x1.z, x1.w};
  float* op = out + (size_t)pixel * CH + c0;
  float r[8];
#pragma unroll
  for (int q = 0; q < 8; ++q) r[q] = m * xv[q] + (1.f - m) * o[q];
  *(float4*)op = make_float4(r[0], r[1], r[2], r[3]);
  *(float4*)(op + 4) = make_float4(r[4], r[5], r[6], r[7]);
}

// ================================================================ launch
extern "C" void kernel_launch(void* const* d_in, const int* in_sizes, int n_in,
                              void* d_out, int out_size, void* d_ws, size_t ws_size,
                              hipStream_t stream) {
  (void)in_sizes; (void)n_in; (void)out_size; (void)ws_size;
  const float* x    = (const float*)d_in[0];
  const float* mask = (const float*)d_in[1];
  const float* wg   = (const float*)d_in[2];
  const float* bg   = (const float*)d_in[3];
  const float* wt   = (const float*)d_in[4];
  const float* bt   = (const float*)d_in[5];
  const float* wp   = (const float*)d_in[6];
  const float* bp   = (const float*)d_in[7];
  const float* ww   = (const float*)d_in[8];
  const float* bw   = (const float*)d_in[9];
  const float* rw1  = (const float*)d_in[10];
  const float* rb1  = (const float*)d_in[11];
  const float* rg1  = (const float*)d_in[12];
  const float* rbe1 = (const float*)d_in[13];
  const float* rw2  = (const float*)d_in[14];
  const float* rb2  = (const float*)d_in[15];
  const float* rg2  = (const float*)d_in[16];
  const float* rbe2 = (const float*)d_in[17];
  float* out = (float*)d_out;

  char* W = (char*)d_ws;
  unsigned short* wfrag = (unsigned short*)W;                     // 58*32 KB = 1.81 MB
  char* base = W + 2097152;
  unsigned short* thb   = (unsigned short*)(base);                // 2 MB
  unsigned short* phb   = (unsigned short*)(base + 2097152);      // 2 MB
  unsigned short* vtb   = (unsigned short*)(base + 2 * 2097152);  // 2 MB
  float*          partL = (float*)(base + 3 * 2097152);           // 256 KB
  unsigned short* partO = (unsigned short*)(base + 3 * 2097152 + 262144);  // 16 MB
  // aliases over dead regions
  float*          wy0   = (float*)(base);                          // 4 MB over thb+phb
  unsigned short* wyb   = (unsigned short*)(base + 2 * 2097152);   // 2 MB over vtb
  unsigned short* c1    = partO;                                   // 2 MB
  unsigned short* c2    = (unsigned short*)((char*)partO + 2097152);       // 2 MB
  float*          partA = (float*)((char*)partO + 2 * 2097152);    // 256 KB
  float*          partB = (float*)((char*)partO + 2 * 2097152 + 262144);   // 256 KB
  float*          wy1   = (float*)((char*)partO + 5 * 1048576);    // 4 MB

  k_prepw<<<232, 256, 0, stream>>>(rw1, rw2, wt, wp, wg, ww, wfrag);
  k_proj3<<<256, 256, 0, stream>>>(x, mask, wfrag, bt, bp, bg, thb, phb, vtb);
  k_attn<<<512, 256, 0, stream>>>(thb, phb, vtb, partO, partL);
  k_gemmW<<<256, 256, 0, stream>>>(partO, partL, wfrag, bw, wy0, wyb);

  const unsigned short* wf1_0 = wfrag;
  const unsigned short* wf2_0 = wfrag + (size_t)1 * 9 * 16384;
  const unsigned short* wf1_1 = wfrag + (size_t)2 * 9 * 16384;
  const unsigned short* wf2_1 = wfrag + (size_t)3 * 9 * 16384;
  const unsigned short* wf1_2 = wfrag + (size_t)4 * 9 * 16384;
  const unsigned short* wf2_2 = wfrag + (size_t)5 * 9 * 16384;

  // block 0
  k_conv<0><<<256, 512, 0, stream>>>(wyb, wf1_0, rb1, nullptr, nullptr, nullptr,
                                     c1, partA, nullptr, nullptr);
  k_conv<1><<<256, 512, 0, stream>>>(c1, wf2_0, rb2, partA, rg1, rbe1,
                                     c2, partB, nullptr, nullptr);
  // block 1 (conv1 fuses residual(0): wy0 -> wy1)
  k_conv<2><<<256, 512, 0, stream>>>(c2, wf1_1, rb1 + 128, partB, rg2, rbe2,
                                     c1, partA, wy0, wy1);
  k_conv<1><<<256, 512, 0, stream>>>(c1, wf2_1, rb2 + 128, partA, rg1 + 128,
                                     rbe1 + 128, c2, partB, nullptr, nullptr);
  // block 2 (conv1 fuses residual(1): wy1 -> wy0)
  k_conv<2><<<256, 512, 0, stream>>>(c2, wf1_2, rb1 + 256, partB, rg2 + 128,
                                     rbe2 + 128, c1, partA, wy1, wy0);
  k_conv<1><<<256, 512, 0, stream>>>(c1, wf2_2, rb2 + 256, partA, rg1 + 256,
                                     rbe1 + 256, c2, partB, nullptr, nullptr);
  // final residual(2) + blend
  k_residual_final<<<512, 256, 0, stream>>>(c2, partB, rg2 + 256, rbe2 + 256,
                                            wy0, x, mask, out);
}